// Round 14
// baseline (439.348 us; speedup 1.0000x reference)
//
#include <hip/hip_runtime.h>
#include <hip/hip_bf16.h>

typedef __hip_bfloat16 bf16;
typedef __attribute__((ext_vector_type(8))) short short8;   // 8 bf16 (MFMA A/B frag)
typedef __attribute__((ext_vector_type(4))) float f32x4;    // MFMA C/D frag
typedef __attribute__((ext_vector_type(4))) short short4v;

#define NREL 460
#define KP   480      // padded K for attn GEMM (15*32)
#define NENT 20000
#define NENT_PAD 20224  // 158*128
#define NB   4096

__device__ inline float sigmoidf_(float x){ return 1.f/(1.f+__expf(-x)); }

// async global->LDS, 16B per lane. LDS dest = wave-uniform base + lane*16.
__device__ inline void gload16(const bf16* g, bf16* l){
  __builtin_amdgcn_global_load_lds(
      (const __attribute__((address_space(1))) unsigned int*)g,
      (__attribute__((address_space(3))) unsigned int*)l, 16, 0, 0);
}

// ---------- fp32 tiled GEMM body (LDS passed in: As/Bs each 32*68 floats) ----------
// 64x64 tile, 256 threads, 4x4 outputs/thread, K-tile 32 staged in LDS.
// mode 0: C = acc + bias
// mode 1: C = acc (f32) AND ct_out[col*KP+row] = bf16(acc) row<NREL, 0 row<KP
// mode 2: C = 0.1*(acc + bias) + add_src
__device__ __forceinline__ void fgemm_body(
    const float* __restrict__ A, int lda, int arows,
    const float* __restrict__ B, int ldb,
    const float* __restrict__ bias,
    float* __restrict__ C, int ldc, int K, int mode,
    const float* __restrict__ add_src, bf16* __restrict__ ct_out,
    float* As, float* Bs, int bx, int by)
{
  const int tid = threadIdx.x;
  const int row0 = bx*64, col0 = by*64;
  const int tx = tid & 15, ty = tid >> 4;
  float acc[4][4] = {};
  for (int k0 = 0; k0 < K; k0 += 32){
    __syncthreads();
    #pragma unroll
    for (int s = 0; s < 2; ++s){
      int slot = tid + s*256;
      int r = slot >> 3, c4 = (slot & 7)*4;
      int ra = row0 + r; if (ra >= arows) ra = arows - 1;
      float4 v = *(const float4*)(A + (long)ra*lda + k0 + c4);
      As[(c4+0)*68+r] = v.x; As[(c4+1)*68+r] = v.y; As[(c4+2)*68+r] = v.z; As[(c4+3)*68+r] = v.w;
      float4 w = *(const float4*)(B + (long)(col0 + r)*ldb + k0 + c4);
      Bs[(c4+0)*68+r] = w.x; Bs[(c4+1)*68+r] = w.y; Bs[(c4+2)*68+r] = w.z; Bs[(c4+3)*68+r] = w.w;
    }
    __syncthreads();
    #pragma unroll
    for (int kk = 0; kk < 32; ++kk){
      float4 a4 = *(const float4*)(&As[kk*68 + ty*4]);
      float4 b4 = *(const float4*)(&Bs[kk*68 + tx*4]);
      float av[4] = {a4.x, a4.y, a4.z, a4.w};
      float bv[4] = {b4.x, b4.y, b4.z, b4.w};
      #pragma unroll
      for (int i = 0; i < 4; ++i)
        #pragma unroll
        for (int j = 0; j < 4; ++j) acc[i][j] += av[i]*bv[j];
    }
  }
  const int rb = row0 + ty*4, cb = col0 + tx*4;
  if (mode == 1){
    #pragma unroll
    for (int i = 0; i < 4; ++i){
      float4 v = {acc[i][0], acc[i][1], acc[i][2], acc[i][3]};
      *(float4*)(C + (long)(rb+i)*ldc + cb) = v;
      int rr = rb + i;
      if (rr < KP){
        #pragma unroll
        for (int j = 0; j < 4; ++j)
          ct_out[(cb+j)*KP + rr] = __float2bfloat16(rr < NREL ? acc[i][j] : 0.f);
      }
    }
  } else if (mode == 2){
    #pragma unroll
    for (int i = 0; i < 4; ++i){
      float4 v;
      #pragma unroll
      for (int j = 0; j < 4; ++j)
        ((float*)&v)[j] = 0.1f*(acc[i][j] + bias[cb+j]) + add_src[(long)(rb+i)*ldc + cb+j];
      *(float4*)(C + (long)(rb+i)*ldc + cb) = v;
    }
  } else {
    float bv[4] = {0,0,0,0};
    if (bias){ bv[0]=bias[cb]; bv[1]=bias[cb+1]; bv[2]=bias[cb+2]; bv[3]=bias[cb+3]; }
    #pragma unroll
    for (int i = 0; i < 4; ++i){
      float4 v = {acc[i][0]+bv[0], acc[i][1]+bv[1], acc[i][2]+bv[2], acc[i][3]+bv[3]};
      *(float4*)(C + (long)(rb+i)*ldc + cb) = v;
    }
  }
}

struct FDesc {
  const float* A; const float* B; const float* bias; float* C;
  const float* add; bf16* ct;
  int lda, ldb, ldc, K, arows, mode;
};

// ---------- MFMA GEMM body, 128x128 tile, 3-buffer 2-deep pipeline ----------
// (used for gi + aligned GEMMs; granule-swizzled LDS per R13)
template<int MODE>
__device__ __forceinline__ void gemm128_body(
    const bf16* __restrict__ A, int lda,
    const bf16* __restrict__ B, int ldb,
    const float* __restrict__ bias,
    void* __restrict__ C, long ldc,
    int K, int n_valid, double* __restrict__ sp_sum,
    const int* __restrict__ trips,
    bf16* sbuf, float* wsum, int bx, int by)
{
  const int tid = threadIdx.x;
  const int lane = tid & 63, wave = tid >> 6;
  const long row0 = (long)bx * 128;
  const long col0 = (long)by * 128;
  const int sr = tid >> 2;                       // staging row 0..63
  const int sc = ((tid & 3) ^ ((sr >> 1) & 3)) * 8;   // pre-swizzled source granule
  const bf16* Ag0 = A + (row0 + sr)*lda + sc;
  const bf16* Ag1 = A + (row0 + 64 + sr)*lda + sc;
  const bf16* Bg0 = B + (col0 + sr)*ldb + sc;
  const bf16* Bg1 = B + (col0 + 64 + sr)*ldb + sc;
  bf16* As_ = sbuf;           // [3][4096]
  bf16* Bs_ = sbuf + 12288;   // [3][4096]
  const int wr = (wave >> 1)*64, wc = (wave & 1)*64;
  const int rA = lane & 15;
  const int kA = ((lane >> 4) ^ ((rA >> 1) & 3)) * 8;  // swizzled read granule
  f32x4 acc[4][4] = {};
  const int nt = K >> 5;
  auto stage = [&](int t, int buf){
    const int k0 = t << 5;
    gload16(Ag0 + k0, As_ + buf*4096 + tid*8);
    gload16(Ag1 + k0, As_ + buf*4096 + 2048 + tid*8);
    gload16(Bg0 + k0, Bs_ + buf*4096 + tid*8);
    gload16(Bg1 + k0, Bs_ + buf*4096 + 2048 + tid*8);
  };
  stage(0, 0); stage(1, 1);
  int cur = 0;
  for (int t = 0; t < nt; ++t){
    if (t + 2 < nt){
      int nb = cur + 2; if (nb >= 3) nb -= 3;
      stage(t + 2, nb);
      asm volatile("s_waitcnt vmcnt(8)" ::: "memory");   // tile t done (8 newer in flight)
    } else if (t + 2 == nt){
      asm volatile("s_waitcnt vmcnt(4)" ::: "memory");
    } else {
      asm volatile("s_waitcnt vmcnt(0)" ::: "memory");
    }
    __builtin_amdgcn_s_barrier();                        // tile t visible
    short8 a[4], b[4];
    #pragma unroll
    for (int m = 0; m < 4; ++m) a[m] = *(const short8*)(As_ + cur*4096 + (wr + m*16 + rA)*32 + kA);
    #pragma unroll
    for (int n = 0; n < 4; ++n) b[n] = *(const short8*)(Bs_ + cur*4096 + (wc + n*16 + rA)*32 + kA);
    asm volatile("s_waitcnt lgkmcnt(0)" ::: "memory");   // frags in regs
    __builtin_amdgcn_s_barrier();                        // buf free for restage
    #pragma unroll
    for (int m = 0; m < 4; ++m)
      #pragma unroll
      for (int n = 0; n < 4; ++n)
        acc[m][n] = __builtin_amdgcn_mfma_f32_16x16x32_bf16(a[m], b[n], acc[m][n], 0,0,0);
    if (++cur == 3) cur = 0;
  }
  const int ri = (lane >> 4)*4, ci = lane & 15;
  __syncthreads();   // staging LDS -> epilogue bounce buffer
  if constexpr (MODE == 1){
    bf16* epi = sbuf + wave*1152;         // 16 rows x 72 bf16
    const int rrow = lane >> 2, q = lane & 3;
    #pragma unroll
    for (int m = 0; m < 4; ++m){
      #pragma unroll
      for (int n = 0; n < 4; ++n){
        long c = col0 + wc + n*16 + ci;
        float bv = bias ? bias[c] : 0.f;
        #pragma unroll
        for (int i = 0; i < 4; ++i)
          epi[(ri+i)*72 + n*16 + ci] = __float2bfloat16(acc[m][n][i] + bv);
      }
      long gr = row0 + wr + m*16 + rrow;
      bf16* gp = (bf16*)C + gr*ldc + col0 + wc + q*16;
      const bf16* lp = epi + rrow*72 + q*16;
      *(short8*)(gp)     = *(const short8*)(lp);
      *(short8*)(gp + 8) = *(const short8*)(lp + 8);
    }
  } else {
    float* epi = (float*)sbuf + wave*1088;   // 16 rows x 68 f32, cols shifted +2
    const int rrow = lane >> 2, q = lane & 3;
    const bool maybe = (col0 + wc) < 464;
    float spart = 0.f, ppart = 0.f;
    #pragma unroll
    for (int m = 0; m < 4; ++m){
      int obj[4];
      if (maybe){
        #pragma unroll
        for (int i = 0; i < 4; ++i)
          obj[i] = trips[3*(int)(row0 + wr + m*16 + ri + i) + 2];
      }
      #pragma unroll
      for (int n = 0; n < 4; ++n){
        long c = col0 + wc + n*16 + ci;
        bool cv = (c < n_valid);
        #pragma unroll
        for (int i = 0; i < 4; ++i){
          float v = acc[m][n][i];
          float sg = 0.f;
          if (cv){
            float e = __expf(-fabsf(v));
            float tt = 1.f + e;
            float rr = __builtin_amdgcn_rcpf(tt);
            sg = (v >= 0.f) ? rr : 1.f - rr;
            spart += fmaxf(v, 0.f) + e*(0.9404f - 0.2537f*e);
            if (maybe && c == obj[i]) ppart += v;
          }
          epi[(ri+i)*68 + n*16 + ci + 2] = sg;
        }
      }
      long gr = row0 + wr + m*16 + rrow;
      long c16 = col0 + wc + q*16;
      if (c16 < n_valid){
        float* gp = (float*)C + gr*ldc + c16;
        const float* lp = epi + rrow*68 + q*16 + 2;
        *(float2*)(gp)      = *(const float2*)(lp);
        *(float4*)(gp + 2)  = *(const float4*)(lp + 2);
        *(float4*)(gp + 6)  = *(const float4*)(lp + 6);
        *(float4*)(gp + 10) = *(const float4*)(lp + 10);
        *(float2*)(gp + 14) = *(const float2*)(lp + 14);
      }
    }
    #pragma unroll
    for (int off = 32; off >= 1; off >>= 1){
      spart += __shfl_xor(spart, off);
      ppart += __shfl_xor(ppart, off);
    }
    if (lane == 0){ wsum[wave] = spart; wsum[4+wave] = ppart; }
    __syncthreads();
    if (tid == 0)
      atomicAdd(sp_sum, (double)(wsum[0]+wsum[1]+wsum[2]+wsum[3]));
    if (tid == 1)
      atomicAdd(sp_sum+1, (double)(wsum[4]+wsum[5]+wsum[6]+wsum[7]));
  }
}

// ---------- score body: K=256 compile-time. A-tile (128x256, 64KB) fully
// LDS-resident (staged once, granule-swizzled); K-loop is BARRIER-FREE:
// B frags stream global->registers (2-deep rotation, compiler-counted vmcnt),
// A frags via conflict-free ds_read_b128. Waves fully decoupled (m233: the
// 2-barrier structure's stage+vmcnt+barrier overhead was ~72% of time).
__device__ __forceinline__ void score_body(
    const bf16* __restrict__ P, const bf16* __restrict__ Q,
    float* __restrict__ C, long ldc, int n_valid,
    double* __restrict__ sp_sum, const int* __restrict__ trips,
    bf16* Alds, float* wsum, int bx, int by)
{
  const int tid = threadIdx.x;
  const int lane = tid & 63, wave = tid >> 6;
  const long row0 = (long)bx * 128;
  const long col0 = (long)by * 128;
  // stage A fully: LDS granule (row, gk) <- global granule (row, gk^(row&7))
  #pragma unroll
  for (int i = 0; i < 16; ++i){
    int G = i*256 + tid;
    int row = G >> 5, gk = G & 31;
    gload16(P + (row0 + row)*256 + ((gk ^ (row & 7)) << 3), Alds + (size_t)G*8);
  }
  asm volatile("s_waitcnt vmcnt(0)" ::: "memory");
  __builtin_amdgcn_s_barrier();
  const int wr = (wave >> 1)*64, wc = (wave & 1)*64;
  const int rA = lane & 15, q4 = lane >> 4, xg = rA & 7;
  const bf16* B0p = Q + (col0 + wc +  0 + rA)*256 + q4*8;
  const bf16* B1p = Q + (col0 + wc + 16 + rA)*256 + q4*8;
  const bf16* B2p = Q + (col0 + wc + 32 + rA)*256 + q4*8;
  const bf16* B3p = Q + (col0 + wc + 48 + rA)*256 + q4*8;
  f32x4 acc[4][4] = {};
  short8 bn1[4], bn2[4];
  bn1[0] = *(const short8*)(B0p);      bn1[1] = *(const short8*)(B1p);
  bn1[2] = *(const short8*)(B2p);      bn1[3] = *(const short8*)(B3p);
  bn2[0] = *(const short8*)(B0p + 32); bn2[1] = *(const short8*)(B1p + 32);
  bn2[2] = *(const short8*)(B2p + 32); bn2[3] = *(const short8*)(B3p + 32);
  #pragma unroll
  for (int t = 0; t < 8; ++t){
    short8 bc[4];
    #pragma unroll
    for (int n = 0; n < 4; ++n){ bc[n] = bn1[n]; bn1[n] = bn2[n]; }
    if (t + 2 < 8){
      const int k0 = (t + 2) * 32;
      bn2[0] = *(const short8*)(B0p + k0); bn2[1] = *(const short8*)(B1p + k0);
      bn2[2] = *(const short8*)(B2p + k0); bn2[3] = *(const short8*)(B3p + k0);
    }
    short8 a[4];
    #pragma unroll
    for (int m = 0; m < 4; ++m){
      int row = wr + m*16 + rA;
      a[m] = *(const short8*)(Alds + row*256 + (((t*4 + q4) ^ xg) << 3));
    }
    #pragma unroll
    for (int m = 0; m < 4; ++m)
      #pragma unroll
      for (int n = 0; n < 4; ++n)
        acc[m][n] = __builtin_amdgcn_mfma_f32_16x16x32_bf16(a[m], bc[n], acc[m][n], 0,0,0);
  }
  // epilogue: sigmoid -> f32 out (LDS-bounced), softplus + pos sums
  const int ri = (lane >> 4)*4, ci = lane & 15;
  __syncthreads();   // all waves done reading Alds
  float* epi = (float*)Alds + wave*1088;   // 16 rows x 68 f32, cols shifted +2
  const int rrow = lane >> 2, q = lane & 3;
  const bool maybe = (col0 + wc) < 464;
  float spart = 0.f, ppart = 0.f;
  #pragma unroll
  for (int m = 0; m < 4; ++m){
    int obj[4];
    if (maybe){
      #pragma unroll
      for (int i = 0; i < 4; ++i)
        obj[i] = trips[3*(int)(row0 + wr + m*16 + ri + i) + 2];
    }
    #pragma unroll
    for (int n = 0; n < 4; ++n){
      long c = col0 + wc + n*16 + ci;
      bool cv = (c < n_valid);
      #pragma unroll
      for (int i = 0; i < 4; ++i){
        float v = acc[m][n][i];
        float sg = 0.f;
        if (cv){
          float e = __expf(-fabsf(v));
          float tt = 1.f + e;
          float rr = __builtin_amdgcn_rcpf(tt);
          sg = (v >= 0.f) ? rr : 1.f - rr;
          spart += fmaxf(v, 0.f) + e*(0.9404f - 0.2537f*e);
          if (maybe && c == obj[i]) ppart += v;
        }
        epi[(ri+i)*68 + n*16 + ci + 2] = sg;
      }
    }
    long gr = row0 + wr + m*16 + rrow;
    long c16 = col0 + wc + q*16;
    if (c16 < n_valid){
      float* gp = C + gr*ldc + c16;
      const float* lp = epi + rrow*68 + q*16 + 2;
      *(float2*)(gp)      = *(const float2*)(lp);
      *(float4*)(gp + 2)  = *(const float4*)(lp + 2);
      *(float4*)(gp + 6)  = *(const float4*)(lp + 6);
      *(float4*)(gp + 10) = *(const float4*)(lp + 10);
      *(float2*)(gp + 14) = *(const float2*)(lp + 14);
    }
  }
  #pragma unroll
  for (int off = 32; off >= 1; off >>= 1){
    spart += __shfl_xor(spart, off);
    ppart += __shfl_xor(ppart, off);
  }
  if (lane == 0){ wsum[wave] = spart; wsum[4+wave] = ppart; }
  __syncthreads();
  if (tid == 0)
    atomicAdd(sp_sum, (double)(wsum[0]+wsum[1]+wsum[2]+wsum[3]));
  if (tid == 1)
    atomicAdd(sp_sum+1, (double)(wsum[4]+wsum[5]+wsum[6]+wsum[7]));
}

// ---------- dispatch 1: conversions + pad/acc zero + G1 GEMM ----------
__global__ __launch_bounds__(256) void k_conv_g1(
    const float4* __restrict__ s0, short4v* __restrict__ d0, int n0,
    const float4* __restrict__ s1, short4v* __restrict__ d1, int n1,
    const float4* __restrict__ s2, short4v* __restrict__ d2, int n2,
    short4v* __restrict__ pad0, int n3, double* __restrict__ dz,
    const float* __restrict__ gA, const float* __restrict__ gB,
    const float* __restrict__ gbias, float* __restrict__ gC)
{
  __shared__ __align__(16) float As[32*68];
  __shared__ __align__(16) float Bs[32*68];
  int bid = blockIdx.x;
  if (bid < 64){
    fgemm_body(gA,256,NREL, gB,256, gbias, gC,512, 256, 0, nullptr,nullptr,
               As, Bs, bid&7, bid>>3);
    return;
  }
  int i = (bid-64)*256 + threadIdx.x;
  if (i < n0+n1+n2){
    const float4* s; short4v* d; int j;
    if (i < n0){ s = s0; d = d0; j = i; }
    else if (i < n0+n1){ s = s1; d = d1; j = i-n0; }
    else { s = s2; d = d2; j = i-n0-n1; }
    float4 v = s[j];
    bf16 a = __float2bfloat16(v.x), b = __float2bfloat16(v.y);
    bf16 c = __float2bfloat16(v.z), e = __float2bfloat16(v.w);
    short4v o; o.x = *(short*)&a; o.y = *(short*)&b; o.z = *(short*)&c; o.w = *(short*)&e;
    d[j] = o;
  } else if (i < n0+n1+n2+n3){
    short4v z = {0,0,0,0};
    pad0[i - (n0+n1+n2)] = z;
  } else if (i < n0+n1+n2+n3+8){
    dz[i - (n0+n1+n2+n3)] = 0.0;   // dsum[0..2] + ticket counters
  }
}

__global__ __launch_bounds__(256) void k_fgemm(
    const float* A, int lda, int arows, const float* B, int ldb,
    const float* bias, float* C, int ldc, int K, int mode,
    const float* add_src, bf16* ct_out){
  __shared__ __align__(16) float As[32*68];
  __shared__ __align__(16) float Bs[32*68];
  fgemm_body(A, lda, arows, B, ldb, bias, C, ldc, K, mode, add_src, ct_out,
             As, Bs, blockIdx.x, blockIdx.y);
}

__global__ __launch_bounds__(256) void k_fgemm_multi(FDesc d0, FDesc d1, FDesc d2,
                                                     int y1, int y2){
  __shared__ __align__(16) float As[32*68];
  __shared__ __align__(16) float Bs[32*68];
  int y = blockIdx.y;
  FDesc d; int by;
  if (y < y1){ d = d0; by = y; }
  else if (y < y2){ d = d1; by = y - y1; }
  else { d = d2; by = y - y2; }
  fgemm_body(d.A, d.lda, d.arows, d.B, d.ldb, d.bias, d.C, d.ldc, d.K, d.mode,
             d.add, d.ct, As, Bs, blockIdx.x, by);
}

// ---------- dispatch 3: G3 multi (160 blocks) + aligned MFMA GEMM (316 blocks) ----------
__global__ __launch_bounds__(256) void k_g3_aligned(
    FDesc d0, FDesc d1, FDesc d2, int y1, int y2,
    const bf16* __restrict__ pA, const bf16* __restrict__ pB,
    const float* __restrict__ pbias, bf16* __restrict__ pC)
{
  __shared__ __align__(16) char smem[49152 + 32];
  int bid = blockIdx.x;
  if (bid < 160){
    int bx = bid & 7, y = bid >> 3;
    FDesc d; int by;
    if (y < y1){ d = d0; by = y; }
    else if (y < y2){ d = d1; by = y - y1; }
    else { d = d2; by = y - y2; }
    fgemm_body(d.A, d.lda, d.arows, d.B, d.ldb, d.bias, d.C, d.ldc, d.K, d.mode,
               d.add, d.ct, (float*)smem, (float*)(smem + 17408), bx, by);
  } else {
    int idx = bid - 160;
    gemm128_body<1>(pA, 256, pB, 256, pbias, pC, 256, 256, 0, nullptr, nullptr,
                    (bf16*)smem, (float*)(smem + 49152), idx % 158, idx / 158);
  }
}

// ---------- dispatch 6: softmax (blocks [0,NB/4)) + make_p with inline h2 ----------
__global__ __launch_bounds__(256) void k_soft_makep(const float* __restrict__ partial,
    const float* __restrict__ attn_base, const int* __restrict__ trips,
    bf16* __restrict__ attn_all,
    const bf16* __restrict__ Qbf,
    const float* __restrict__ M_ih, const float* __restrict__ ghp,
    const float* __restrict__ ph, const float* __restrict__ b_ih,
    bf16* __restrict__ P){
  int bid = blockIdx.x;
  if (bid >= NB/4){
    int i = (bid - NB/4)*256 + threadIdx.x;   // 4096*256
    int b = i >> 8, k = i & 255;
    int s = trips[b*3+0], rel = trips[b*3+1];
    long rb = (long)rel*768;
    float rg = sigmoidf_(M_ih[rb+k]     + b_ih[k]     + ghp[rb+k]);
    float zg = sigmoidf_(M_ih[rb+256+k] + b_ih[256+k] + ghp[rb+256+k]);
    float ng = tanhf    (M_ih[rb+512+k] + b_ih[512+k] + rg*ghp[rb+512+k]);
    float h2v = (1.f - zg)*ng + zg*ph[rel*256+k];
    P[i] = __float2bfloat16(__bfloat162float(Qbf[(long)s*256+k]) * h2v);
    return;
  }
  int wave = threadIdx.x >> 6, lane = threadIdx.x & 63;
  int b = bid*4 + wave;
  int rel = trips[b*3+1];
  const float* base = attn_base + (long)rel*512;
  float bs[8];
  #pragma unroll
  for (int s = 0; s < 8; ++s){
    int idx = s*64 + lane;
    bs[s] = (idx < NREL) ? base[idx] : 0.f;
  }
  const float* cur0 = partial + (long)b*4600 + 2*NREL;
  for (int t = 0; t < 8; ++t){
    const float* cur = cur0 + t*NREL;
    float v[8]; float mx = -1e30f;
    #pragma unroll
    for (int s = 0; s < 8; ++s){
      int idx = s*64 + lane;
      float val = -1e30f;
      if (idx < NREL){
        float pz = cur[idx]*bs[s];
        val = (pz == 0.f) ? -1e9f : pz;
      }
      v[s] = val; mx = fmaxf(mx, val);
    }
    #pragma unroll
    for (int off = 32; off >= 1; off >>= 1) mx = fmaxf(mx, __shfl_xor(mx, off));
    float sum = 0.f;
    #pragma unroll
    for (int s = 0; s < 8; ++s){
      int idx = s*64 + lane;
      if (idx < NREL){ v[s] = __expf(v[s]-mx); sum += v[s]; }
    }
    #pragma unroll
    for (int off = 32; off >= 1; off >>= 1) sum += __shfl_xor(sum, off);
    float inv = 1.f/sum;
    long obase = ((long)t*NB + b)*KP;
    #pragma unroll
    for (int s = 0; s < 8; ++s){
      int idx = s*64 + lane;
      if (idx < KP) attn_all[obase + idx] = __float2bfloat16(idx < NREL ? v[s]*inv : 0.f);
    }
  }
}

// ---------- dispatch 7: score (5056 blocks, barrier-free body) + gi GEMM (1536) ----------
__global__ __launch_bounds__(256) void k_gemm_dual(
    const bf16* __restrict__ A2, const bf16* __restrict__ B2,
    void* __restrict__ C2, long ldc2, int K2, int nvalid2,
    double* __restrict__ sp, const int* __restrict__ trips, int nblk2,
    const bf16* __restrict__ A1, const bf16* __restrict__ B1,
    const float* __restrict__ bias1, void* __restrict__ C1, long ldc1, int K1)
{
  __shared__ __align__(16) bf16 sbuf[32768];   // 64KB (score: full A tile)
  __shared__ float wsum[8];
  int bid = blockIdx.x;
  if (bid < nblk2){
    score_body(A2, B2, (float*)C2, ldc2, nvalid2, sp, trips,
               sbuf, wsum, bid & 31, bid >> 5);
  } else {
    int idx = bid - nblk2;
    gemm128_body<1>(A1, KP, B1, KP, bias1, C1, ldc1, K1, 0, nullptr, nullptr,
                    sbuf, wsum, idx & 255, idx >> 8);
  }
}

// ---------- dispatch 8: fused 8-step GRU scan + match loss + final (ticket) ----------
__global__ __launch_bounds__(512) void k_scan(
    const bf16* __restrict__ gi_all,       // [8*NB][768], b_ih folded in
    const bf16* __restrict__ W_hh_bf,      // [768][256]
    const float* __restrict__ b_hh,
    const float* __restrict__ ph,          // [512][256] rows<460 valid
    const int* __restrict__ trips,
    double* __restrict__ dsum, int* __restrict__ done, float* __restrict__ outf)
{
  __shared__ __align__(16) bf16 hl[16*264];
  __shared__ __align__(16) bf16 gbuf[2][16*768];
  __shared__ float red[8];
  const int tid = threadIdx.x;
  const int lane = tid & 63, wave = tid >> 6;
  const int brow0 = blockIdx.x * 16;
  const int rA = lane & 15, kA = (lane >> 4) * 8;
  const int ci = lane & 15, rbase = (lane >> 4) * 4;
  float hreg[2][4] = {};
  float bh[3][2];
  #pragma unroll
  for (int f = 0; f < 2; ++f){
    int cf = wave*32 + f*16 + ci;
    bh[0][f] = b_hh[cf]; bh[1][f] = b_hh[256+cf]; bh[2][f] = b_hh[512+cf];
  }
  // preload W-frags for k-slices 0..5 (144 VGPR); slices 6,7 streamed from L2
  short8 warr[3][2][6];
  #pragma unroll
  for (int g = 0; g < 3; ++g)
    #pragma unroll
    for (int f = 0; f < 2; ++f)
      #pragma unroll
      for (int k = 0; k < 6; ++k)
        warr[g][f][k] = *(const short8*)(W_hh_bf + (g*256 + wave*32 + f*16 + rA)*256 + k*32 + kA);
  {
    const bf16* src = gi_all + (long)brow0 * 768;
    #pragma unroll
    for (int i = 0; i < 3; ++i){
      int off = (wave*3 + i)*512 + lane*8;
      gload16(src + off, gbuf[0] + off);
    }
  }
  int cur = 0;
  for (int t = 0; t < 8; ++t){
    f32x4 acc[3][2] = {};
    if (t > 0){
      #pragma unroll
      for (int k = 0; k < 8; ++k){
        short8 a = *(const short8*)(hl + rA*264 + k*32 + kA);
        #pragma unroll
        for (int g = 0; g < 3; ++g)
          #pragma unroll
          for (int f = 0; f < 2; ++f){
            short8 b;
            if (k < 6) b = warr[g][f][k];
            else b = *(const short8*)(W_hh_bf + (g*256 + wave*32 + f*16 + rA)*256 + k*32 + kA);
            acc[g][f] = __builtin_amdgcn_mfma_f32_16x16x32_bf16(a, b, acc[g][f], 0,0,0);
          }
      }
    }
    asm volatile("s_waitcnt lgkmcnt(0) vmcnt(0)" ::: "memory"); // hl reads retired; gi(t) staged
    __builtin_amdgcn_s_barrier();
    if (t < 7){
      const bf16* src = gi_all + ((long)(t+1)*NB + brow0) * 768;
      bf16* dst = gbuf[cur ^ 1];
      #pragma unroll
      for (int i = 0; i < 3; ++i){
        int off = (wave*3 + i)*512 + lane*8;
        gload16(src + off, dst + off);
      }
    }
    const bf16* gl = gbuf[cur];
    #pragma unroll
    for (int f = 0; f < 2; ++f){
      int cf = wave*32 + f*16 + ci;
      #pragma unroll
      for (int i = 0; i < 4; ++i){
        int rloc = rbase + i;
        float gir = __bfloat162float(gl[rloc*768 + cf]);
        float giz = __bfloat162float(gl[rloc*768 + 256 + cf]);
        float gin = __bfloat162float(gl[rloc*768 + 512 + cf]);
        float rg = sigmoidf_(gir + acc[0][f][i] + bh[0][f]);
        float zg = sigmoidf_(giz + acc[1][f][i] + bh[1][f]);
        float ng = tanhf(gin + rg*(acc[2][f][i] + bh[2][f]));
        float hn = (1.f - zg)*ng + zg*hreg[f][i];
        hreg[f][i] = hn;
        hl[rloc*264 + cf] = __float2bfloat16(hn);
      }
    }
    asm volatile("s_waitcnt lgkmcnt(0)" ::: "memory");  // hl writes + gbuf reads retired
    __builtin_amdgcn_s_barrier();
    cur ^= 1;
  }
  float d = 0.f;
  #pragma unroll
  for (int f = 0; f < 2; ++f){
    int cf = wave*32 + f*16 + ci;
    #pragma unroll
    for (int i = 0; i < 4; ++i){
      int rel = trips[(brow0 + rbase + i)*3 + 1];
      float diff = ph[rel*256 + cf] - hreg[f][i];
      d += diff*diff;
    }
  }
  #pragma unroll
  for (int off = 32; off >= 1; off >>= 1) d += __shfl_xor(d, off);
  if (lane == 0) red[wave] = d;
  __syncthreads();
  if (tid == 0){
    float s = 0.f;
    #pragma unroll
    for (int w = 0; w < 8; ++w) s += red[w];
    atomicAdd(dsum, (double)s);
    asm volatile("s_waitcnt vmcnt(0)" ::: "memory");     // dsum add at coherent point
    int ticket = atomicAdd(done, 1);
    if (ticket == (int)gridDim.x - 1){
      double m  = atomicAdd(dsum+0, 0.0);                // coherent RMW reads
      double sp = atomicAdd(dsum+1, 0.0);
      double pp = atomicAdd(dsum+2, 0.0);
      outf[0] = (float)(m / (4096.0*256.0));
      outf[1] = (float)((sp - pp) / (4096.0*20000.0));
    }
  }
}

extern "C" void kernel_launch(void* const* d_in, const int* in_sizes, int n_in,
                              void* d_out, int out_size, void* d_ws, size_t ws_size,
                              hipStream_t stream){
  const float* pre_emb = (const float*)d_in[0];
  const float* r_emb   = (const float*)d_in[1];
  const float* partial = (const float*)d_in[2];
  const float* W_map1  = (const float*)d_in[3];
  const float* b_map1  = (const float*)d_in[4];
  const float* W_map2  = (const float*)d_in[5];
  const float* b_map2  = (const float*)d_in[6];
  const float* W_h1    = (const float*)d_in[7];
  const float* b_h1    = (const float*)d_in[8];
  const float* W_h2    = (const float*)d_in[9];
  const float* b_h2    = (const float*)d_in[10];
  const float* W_attn  = (const float*)d_in[11];
  const float* b_attn  = (const float*)d_in[12];
  const float* W_align = (const float*)d_in[13];
  const float* b_align = (const float*)d_in[14];
  const float* W_ih    = (const float*)d_in[15];
  const float* W_hh    = (const float*)d_in[16];
  const float* b_ih    = (const float*)d_in[17];
  const float* b_hh    = (const float*)d_in[18];
  const int*   trips   = (const int*)d_in[19];
  float* out = (float*)d_out;

  // ---- workspace layout ----
  char* w = (char*)d_ws;
  auto alloc = [&](size_t bytes)->char*{
    char* r = w; w += (bytes + 255) & ~size_t(255); return r;
  };
  double* dsum      = (double*)alloc(128);   // [0]=match [1]=softplus [2]=pos, [4..]=ticket
  int*    done      = (int*)(dsum + 4);
  float* t1         = (float*)alloc(512*512*4);
  float* mapped     = (float*)alloc(512*256*4);
  float* a1         = (float*)alloc(512*256*4);
  float* th         = (float*)alloc(512*256*4);
  float* ph         = (float*)alloc(512*256*4);
  float* M_ih       = (float*)alloc(512*768*4);
  float* ghp        = (float*)alloc(512*768*4);
  float* attn_base  = (float*)alloc(512*512*4);
  bf16*  M_ihT      = (bf16*)alloc(768*KP*2);
  bf16*  W_hh_bf    = (bf16*)alloc(768*256*2);
  bf16*  W_align_bf = (bf16*)alloc(256*256*2);
  bf16*  Q_bf       = (bf16*)alloc((size_t)NENT_PAD*256*2);
  bf16*  P_bf       = (bf16*)alloc((size_t)NB*256*2);
  bf16*  attn_all   = (bf16*)alloc((size_t)8*NB*KP*2);
  bf16*  gi_all     = (bf16*)alloc((size_t)8*NB*768*2);
  bf16*  pre_bf     = attn_all;   // aliased: pre_bf dead before attn_all written

  // ---- dispatch 1: conversions + pad/dsum zero + G1 (t1 = r_emb@W_map1^T + b_map1) ----
  {
    int n0 = NENT*256/4, n1 = 768*256/4, n2 = 256*256/4;
    int n3 = (NENT_PAD-NENT)*256/4;
    int ntot = n0+n1+n2+n3+8;
    k_conv_g1<<<64 + (ntot+255)/256, 256, 0, stream>>>(
        (const float4*)pre_emb, (short4v*)pre_bf, n0,
        (const float4*)W_hh, (short4v*)W_hh_bf, n1,
        (const float4*)W_align, (short4v*)W_align_bf, n2,
        (short4v*)(pre_bf + (size_t)NENT*256), n3, dsum,
        r_emb, W_map1, b_map1, t1);
  }
  // ---- dispatch 2: G2 mapped = t1 @ W_map2^T + b_map2 ----
  k_fgemm<<<dim3(8,4),256,0,stream>>>(t1,512,512, W_map2,512, b_map2, mapped,256, 512, 0, nullptr, nullptr);
  // ---- dispatch 3: G3 {M_ih+M_ihT | a1 | th} + aligned GEMM (Q_bf) ----
  {
    FDesc d0 = { mapped, W_ih,   nullptr, M_ih, nullptr, M_ihT, 256, 256, 768, 256, 512, 1 };
    FDesc d1 = { mapped, W_attn, b_attn,  a1,   nullptr, nullptr, 256, 256, 256, 256, 512, 0 };
    FDesc d2 = { mapped, W_h1,   b_h1,    th,   nullptr, nullptr, 256, 256, 256, 256, 512, 0 };
    k_g3_aligned<<<160 + 316, 256, 0, stream>>>(d0, d1, d2, 12, 16,
                                                pre_bf, W_align_bf, b_align, Q_bf);
  }
  // ---- dispatch 4: G4 {ph} + G5 {attn_base} ----
  {
    FDesc d0 = { th, W_h2,   b_h2,    ph,        mapped,  nullptr, 256, 256, 256, 256, 512, 2 };
    FDesc d1 = { a1, mapped, nullptr, attn_base, nullptr, nullptr, 256, 256, 512, 256, 512, 0 };
    k_fgemm_multi<<<dim3(8,12),256,0,stream>>>(d0, d1, d1, 4, 12);
  }
  // ---- dispatch 5: G6 ghp = ph @ W_hh^T + b_hh ----
  k_fgemm<<<dim3(8,12),256,0,stream>>>(ph,256,512, W_hh,256, b_hh, ghp,768, 256, 0, nullptr, nullptr);
  // ---- dispatch 6: softmax + make_p (inline h2) ----
  k_soft_makep<<<NB/4 + NB,256,0,stream>>>(partial, attn_base, trips, attn_all,
                                           Q_bf, M_ih, ghp, ph, b_ih, P_bf);
  // ---- dispatch 7: score (barrier-free) + gi merged ----
  k_gemm_dual<<<5056 + 1536, 256, 0, stream>>>(
      P_bf, Q_bf, out+2, NENT, 256, NENT, dsum+1, trips, 5056,
      attn_all, M_ihT, b_ih, gi_all, 768, KP);
  // ---- dispatch 8: scan + match loss + final ----
  k_scan<<<NB/16,512,0,stream>>>(gi_all, W_hh_bf, b_hh, ph, trips, dsum, done, out);
}

// Round 15
// 386.860 us; speedup vs baseline: 1.1357x; 1.1357x over previous
//
#include <hip/hip_runtime.h>
#include <hip/hip_bf16.h>

typedef __hip_bfloat16 bf16;
typedef __attribute__((ext_vector_type(8))) short short8;   // 8 bf16 (MFMA A/B frag)
typedef __attribute__((ext_vector_type(4))) float f32x4;    // MFMA C/D frag
typedef __attribute__((ext_vector_type(4))) short short4v;

#define NREL 460
#define KP   480      // padded K for attn GEMM (15*32)
#define NENT 20000
#define NENT_PAD 20224  // 158*128
#define NB   4096

__device__ inline float sigmoidf_(float x){ return 1.f/(1.f+__expf(-x)); }

// async global->LDS, 16B per lane. LDS dest = wave-uniform base + lane*16.
__device__ inline void gload16(const bf16* g, bf16* l){
  __builtin_amdgcn_global_load_lds(
      (const __attribute__((address_space(1))) unsigned int*)g,
      (__attribute__((address_space(3))) unsigned int*)l, 16, 0, 0);
}

// ---------- fp32 tiled GEMM body (LDS passed in: As/Bs each 32*68 floats) ----------
// 64x64 tile, 256 threads, 4x4 outputs/thread, K-tile 32 staged in LDS.
// mode 0: C = acc + bias
// mode 1: C = acc (f32) AND ct_out[col*KP+row] = bf16(acc) row<NREL, 0 row<KP
// mode 2: C = 0.1*(acc + bias) + add_src
__device__ __forceinline__ void fgemm_body(
    const float* __restrict__ A, int lda, int arows,
    const float* __restrict__ B, int ldb,
    const float* __restrict__ bias,
    float* __restrict__ C, int ldc, int K, int mode,
    const float* __restrict__ add_src, bf16* __restrict__ ct_out,
    float* As, float* Bs, int bx, int by)
{
  const int tid = threadIdx.x;
  const int row0 = bx*64, col0 = by*64;
  const int tx = tid & 15, ty = tid >> 4;
  float acc[4][4] = {};
  for (int k0 = 0; k0 < K; k0 += 32){
    __syncthreads();
    #pragma unroll
    for (int s = 0; s < 2; ++s){
      int slot = tid + s*256;
      int r = slot >> 3, c4 = (slot & 7)*4;
      int ra = row0 + r; if (ra >= arows) ra = arows - 1;
      float4 v = *(const float4*)(A + (long)ra*lda + k0 + c4);
      As[(c4+0)*68+r] = v.x; As[(c4+1)*68+r] = v.y; As[(c4+2)*68+r] = v.z; As[(c4+3)*68+r] = v.w;
      float4 w = *(const float4*)(B + (long)(col0 + r)*ldb + k0 + c4);
      Bs[(c4+0)*68+r] = w.x; Bs[(c4+1)*68+r] = w.y; Bs[(c4+2)*68+r] = w.z; Bs[(c4+3)*68+r] = w.w;
    }
    __syncthreads();
    #pragma unroll
    for (int kk = 0; kk < 32; ++kk){
      float4 a4 = *(const float4*)(&As[kk*68 + ty*4]);
      float4 b4 = *(const float4*)(&Bs[kk*68 + tx*4]);
      float av[4] = {a4.x, a4.y, a4.z, a4.w};
      float bv[4] = {b4.x, b4.y, b4.z, b4.w};
      #pragma unroll
      for (int i = 0; i < 4; ++i)
        #pragma unroll
        for (int j = 0; j < 4; ++j) acc[i][j] += av[i]*bv[j];
    }
  }
  const int rb = row0 + ty*4, cb = col0 + tx*4;
  if (mode == 1){
    #pragma unroll
    for (int i = 0; i < 4; ++i){
      float4 v = {acc[i][0], acc[i][1], acc[i][2], acc[i][3]};
      *(float4*)(C + (long)(rb+i)*ldc + cb) = v;
      int rr = rb + i;
      if (rr < KP){
        #pragma unroll
        for (int j = 0; j < 4; ++j)
          ct_out[(cb+j)*KP + rr] = __float2bfloat16(rr < NREL ? acc[i][j] : 0.f);
      }
    }
  } else if (mode == 2){
    #pragma unroll
    for (int i = 0; i < 4; ++i){
      float4 v;
      #pragma unroll
      for (int j = 0; j < 4; ++j)
        ((float*)&v)[j] = 0.1f*(acc[i][j] + bias[cb+j]) + add_src[(long)(rb+i)*ldc + cb+j];
      *(float4*)(C + (long)(rb+i)*ldc + cb) = v;
    }
  } else {
    float bv[4] = {0,0,0,0};
    if (bias){ bv[0]=bias[cb]; bv[1]=bias[cb+1]; bv[2]=bias[cb+2]; bv[3]=bias[cb+3]; }
    #pragma unroll
    for (int i = 0; i < 4; ++i){
      float4 v = {acc[i][0]+bv[0], acc[i][1]+bv[1], acc[i][2]+bv[2], acc[i][3]+bv[3]};
      *(float4*)(C + (long)(rb+i)*ldc + cb) = v;
    }
  }
}

struct FDesc {
  const float* A; const float* B; const float* bias; float* C;
  const float* add; bf16* ct;
  int lda, ldb, ldc, K, arows, mode;
};

// ---------- MFMA GEMM body, 128x128 tile, 2-buffer double-buffered (32KB LDS) ----------
// Granule-swizzled LDS (R13): conflict-free ds_read; occupancy 4 blocks/CU.
template<int MODE>
__device__ __forceinline__ void gemm128_body(
    const bf16* __restrict__ A, int lda,
    const bf16* __restrict__ B, int ldb,
    const float* __restrict__ bias,
    void* __restrict__ C, long ldc,
    int K, int n_valid, double* __restrict__ sp_sum,
    const int* __restrict__ trips,
    bf16* sbuf, float* wsum, int bx, int by)
{
  const int tid = threadIdx.x;
  const int lane = tid & 63, wave = tid >> 6;
  const long row0 = (long)bx * 128;
  const long col0 = (long)by * 128;
  const int sr = tid >> 2;                       // staging row 0..63
  const int sc = ((tid & 3) ^ ((sr >> 1) & 3)) * 8;   // pre-swizzled source granule
  const bf16* Ag0 = A + (row0 + sr)*lda + sc;
  const bf16* Ag1 = A + (row0 + 64 + sr)*lda + sc;
  const bf16* Bg0 = B + (col0 + sr)*ldb + sc;
  const bf16* Bg1 = B + (col0 + 64 + sr)*ldb + sc;
  bf16* As_ = sbuf;          // [2][4096]
  bf16* Bs_ = sbuf + 8192;   // [2][4096]
  const int wr = (wave >> 1)*64, wc = (wave & 1)*64;
  const int rA = lane & 15;
  const int kA = ((lane >> 4) ^ ((rA >> 1) & 3)) * 8;  // swizzled read granule
  f32x4 acc[4][4] = {};
  const int nt = K >> 5;
  gload16(Ag0, As_ + tid*8);
  gload16(Ag1, As_ + 2048 + tid*8);
  gload16(Bg0, Bs_ + tid*8);
  gload16(Bg1, Bs_ + 2048 + tid*8);
  int cur = 0;
  for (int t = 0; t < nt; ++t){
    if (t + 1 < nt){
      const int k0 = (t+1) << 5;
      const int nxt = cur ^ 1;
      gload16(Ag0 + k0, As_ + nxt*4096 + tid*8);
      gload16(Ag1 + k0, As_ + nxt*4096 + 2048 + tid*8);
      gload16(Bg0 + k0, Bs_ + nxt*4096 + tid*8);
      gload16(Bg1 + k0, Bs_ + nxt*4096 + 2048 + tid*8);
      asm volatile("s_waitcnt vmcnt(4)" ::: "memory");   // tile t arrived
    } else {
      asm volatile("s_waitcnt vmcnt(0)" ::: "memory");
    }
    __builtin_amdgcn_s_barrier();                        // tile t visible
    short8 a[4], b[4];
    #pragma unroll
    for (int m = 0; m < 4; ++m) a[m] = *(const short8*)(As_ + cur*4096 + (wr + m*16 + rA)*32 + kA);
    #pragma unroll
    for (int n = 0; n < 4; ++n) b[n] = *(const short8*)(Bs_ + cur*4096 + (wc + n*16 + rA)*32 + kA);
    asm volatile("s_waitcnt lgkmcnt(0)" ::: "memory");   // frags in regs
    __builtin_amdgcn_s_barrier();                        // buf free for restage
    #pragma unroll
    for (int m = 0; m < 4; ++m)
      #pragma unroll
      for (int n = 0; n < 4; ++n)
        acc[m][n] = __builtin_amdgcn_mfma_f32_16x16x32_bf16(a[m], b[n], acc[m][n], 0,0,0);
    cur ^= 1;
  }
  const int ri = (lane >> 4)*4, ci = lane & 15;
  __syncthreads();   // staging LDS -> epilogue bounce buffer
  if constexpr (MODE == 1){
    bf16* epi = sbuf + wave*1152;         // 16 rows x 72 bf16
    const int rrow = lane >> 2, q = lane & 3;
    #pragma unroll
    for (int m = 0; m < 4; ++m){
      #pragma unroll
      for (int n = 0; n < 4; ++n){
        long c = col0 + wc + n*16 + ci;
        float bv = bias ? bias[c] : 0.f;
        #pragma unroll
        for (int i = 0; i < 4; ++i)
          epi[(ri+i)*72 + n*16 + ci] = __float2bfloat16(acc[m][n][i] + bv);
      }
      long gr = row0 + wr + m*16 + rrow;
      bf16* gp = (bf16*)C + gr*ldc + col0 + wc + q*16;
      const bf16* lp = epi + rrow*72 + q*16;
      *(short8*)(gp)     = *(const short8*)(lp);
      *(short8*)(gp + 8) = *(const short8*)(lp + 8);
    }
  } else {
    float* epi = (float*)sbuf + wave*1088;   // 16 rows x 68 f32, cols shifted +2
    const int rrow = lane >> 2, q = lane & 3;
    const bool maybe = (col0 + wc) < 464;
    float spart = 0.f, ppart = 0.f;
    #pragma unroll
    for (int m = 0; m < 4; ++m){
      int obj[4];
      if (maybe){
        #pragma unroll
        for (int i = 0; i < 4; ++i)
          obj[i] = trips[3*(int)(row0 + wr + m*16 + ri + i) + 2];
      }
      #pragma unroll
      for (int n = 0; n < 4; ++n){
        long c = col0 + wc + n*16 + ci;
        bool cv = (c < n_valid);
        #pragma unroll
        for (int i = 0; i < 4; ++i){
          float v = acc[m][n][i];
          float sg = 0.f;
          if (cv){
            float e = __expf(-fabsf(v));
            float tt = 1.f + e;
            float rr = __builtin_amdgcn_rcpf(tt);
            sg = (v >= 0.f) ? rr : 1.f - rr;
            spart += fmaxf(v, 0.f) + e*(0.9404f - 0.2537f*e);
            if (maybe && c == obj[i]) ppart += v;
          }
          epi[(ri+i)*68 + n*16 + ci + 2] = sg;
        }
      }
      long gr = row0 + wr + m*16 + rrow;
      long c16 = col0 + wc + q*16;
      if (c16 < n_valid){
        float* gp = (float*)C + gr*ldc + c16;
        const float* lp = epi + rrow*68 + q*16 + 2;
        *(float2*)(gp)      = *(const float2*)(lp);
        *(float4*)(gp + 2)  = *(const float4*)(lp + 2);
        *(float4*)(gp + 6)  = *(const float4*)(lp + 6);
        *(float4*)(gp + 10) = *(const float4*)(lp + 10);
        *(float2*)(gp + 14) = *(const float2*)(lp + 14);
      }
    }
    #pragma unroll
    for (int off = 32; off >= 1; off >>= 1){
      spart += __shfl_xor(spart, off);
      ppart += __shfl_xor(ppart, off);
    }
    if (lane == 0){ wsum[wave] = spart; wsum[4+wave] = ppart; }
    __syncthreads();
    if (tid == 0)
      atomicAdd(sp_sum, (double)(wsum[0]+wsum[1]+wsum[2]+wsum[3]));
    if (tid == 1)
      atomicAdd(sp_sum+1, (double)(wsum[4]+wsum[5]+wsum[6]+wsum[7]));
  }
}

// ---------- dispatch 1: conversions + pad/acc zero + G1 GEMM ----------
__global__ __launch_bounds__(256) void k_conv_g1(
    const float4* __restrict__ s0, short4v* __restrict__ d0, int n0,
    const float4* __restrict__ s1, short4v* __restrict__ d1, int n1,
    const float4* __restrict__ s2, short4v* __restrict__ d2, int n2,
    short4v* __restrict__ pad0, int n3, double* __restrict__ dz,
    const float* __restrict__ gA, const float* __restrict__ gB,
    const float* __restrict__ gbias, float* __restrict__ gC)
{
  __shared__ __align__(16) float As[32*68];
  __shared__ __align__(16) float Bs[32*68];
  int bid = blockIdx.x;
  if (bid < 64){
    fgemm_body(gA,256,NREL, gB,256, gbias, gC,512, 256, 0, nullptr,nullptr,
               As, Bs, bid&7, bid>>3);
    return;
  }
  int i = (bid-64)*256 + threadIdx.x;
  if (i < n0+n1+n2){
    const float4* s; short4v* d; int j;
    if (i < n0){ s = s0; d = d0; j = i; }
    else if (i < n0+n1){ s = s1; d = d1; j = i-n0; }
    else { s = s2; d = d2; j = i-n0-n1; }
    float4 v = s[j];
    bf16 a = __float2bfloat16(v.x), b = __float2bfloat16(v.y);
    bf16 c = __float2bfloat16(v.z), e = __float2bfloat16(v.w);
    short4v o; o.x = *(short*)&a; o.y = *(short*)&b; o.z = *(short*)&c; o.w = *(short*)&e;
    d[j] = o;
  } else if (i < n0+n1+n2+n3){
    short4v z = {0,0,0,0};
    pad0[i - (n0+n1+n2)] = z;
  } else if (i < n0+n1+n2+n3+8){
    dz[i - (n0+n1+n2+n3)] = 0.0;   // dsum[0..2] + ticket counters
  }
}

__global__ __launch_bounds__(256) void k_fgemm(
    const float* A, int lda, int arows, const float* B, int ldb,
    const float* bias, float* C, int ldc, int K, int mode,
    const float* add_src, bf16* ct_out){
  __shared__ __align__(16) float As[32*68];
  __shared__ __align__(16) float Bs[32*68];
  fgemm_body(A, lda, arows, B, ldb, bias, C, ldc, K, mode, add_src, ct_out,
             As, Bs, blockIdx.x, blockIdx.y);
}

__global__ __launch_bounds__(256) void k_fgemm_multi(FDesc d0, FDesc d1, FDesc d2,
                                                     int y1, int y2){
  __shared__ __align__(16) float As[32*68];
  __shared__ __align__(16) float Bs[32*68];
  int y = blockIdx.y;
  FDesc d; int by;
  if (y < y1){ d = d0; by = y; }
  else if (y < y2){ d = d1; by = y - y1; }
  else { d = d2; by = y - y2; }
  fgemm_body(d.A, d.lda, d.arows, d.B, d.ldb, d.bias, d.C, d.ldc, d.K, d.mode,
             d.add, d.ct, As, Bs, blockIdx.x, by);
}

// ---------- dispatch 3: G3 multi (160 blocks) + aligned MFMA GEMM (316 blocks) ----------
__global__ __launch_bounds__(256) void k_g3_aligned(
    FDesc d0, FDesc d1, FDesc d2, int y1, int y2,
    const bf16* __restrict__ pA, const bf16* __restrict__ pB,
    const float* __restrict__ pbias, bf16* __restrict__ pC)
{
  __shared__ __align__(16) char smem[34816 + 32];
  int bid = blockIdx.x;
  if (bid < 160){
    int bx = bid & 7, y = bid >> 3;
    FDesc d; int by;
    if (y < y1){ d = d0; by = y; }
    else if (y < y2){ d = d1; by = y - y1; }
    else { d = d2; by = y - y2; }
    fgemm_body(d.A, d.lda, d.arows, d.B, d.ldb, d.bias, d.C, d.ldc, d.K, d.mode,
               d.add, d.ct, (float*)smem, (float*)(smem + 17408), bx, by);
  } else {
    int idx = bid - 160;
    gemm128_body<1>(pA, 256, pB, 256, pbias, pC, 256, 256, 0, nullptr, nullptr,
                    (bf16*)smem, (float*)(smem + 34816), idx % 158, idx / 158);
  }
}

// ---------- dispatch 6: softmax (blocks [0,NB/4)) + make_p with inline h2 ----------
__global__ __launch_bounds__(256) void k_soft_makep(const float* __restrict__ partial,
    const float* __restrict__ attn_base, const int* __restrict__ trips,
    bf16* __restrict__ attn_all,
    const bf16* __restrict__ Qbf,
    const float* __restrict__ M_ih, const float* __restrict__ ghp,
    const float* __restrict__ ph, const float* __restrict__ b_ih,
    bf16* __restrict__ P){
  int bid = blockIdx.x;
  if (bid >= NB/4){
    int i = (bid - NB/4)*256 + threadIdx.x;   // 4096*256
    int b = i >> 8, k = i & 255;
    int s = trips[b*3+0], rel = trips[b*3+1];
    long rb = (long)rel*768;
    float rg = sigmoidf_(M_ih[rb+k]     + b_ih[k]     + ghp[rb+k]);
    float zg = sigmoidf_(M_ih[rb+256+k] + b_ih[256+k] + ghp[rb+256+k]);
    float ng = tanhf    (M_ih[rb+512+k] + b_ih[512+k] + rg*ghp[rb+512+k]);
    float h2v = (1.f - zg)*ng + zg*ph[rel*256+k];
    P[i] = __float2bfloat16(__bfloat162float(Qbf[(long)s*256+k]) * h2v);
    return;
  }
  int wave = threadIdx.x >> 6, lane = threadIdx.x & 63;
  int b = bid*4 + wave;
  int rel = trips[b*3+1];
  const float* base = attn_base + (long)rel*512;
  float bs[8];
  #pragma unroll
  for (int s = 0; s < 8; ++s){
    int idx = s*64 + lane;
    bs[s] = (idx < NREL) ? base[idx] : 0.f;
  }
  const float* cur0 = partial + (long)b*4600 + 2*NREL;
  for (int t = 0; t < 8; ++t){
    const float* cur = cur0 + t*NREL;
    float v[8]; float mx = -1e30f;
    #pragma unroll
    for (int s = 0; s < 8; ++s){
      int idx = s*64 + lane;
      float val = -1e30f;
      if (idx < NREL){
        float pz = cur[idx]*bs[s];
        val = (pz == 0.f) ? -1e9f : pz;
      }
      v[s] = val; mx = fmaxf(mx, val);
    }
    #pragma unroll
    for (int off = 32; off >= 1; off >>= 1) mx = fmaxf(mx, __shfl_xor(mx, off));
    float sum = 0.f;
    #pragma unroll
    for (int s = 0; s < 8; ++s){
      int idx = s*64 + lane;
      if (idx < NREL){ v[s] = __expf(v[s]-mx); sum += v[s]; }
    }
    #pragma unroll
    for (int off = 32; off >= 1; off >>= 1) sum += __shfl_xor(sum, off);
    float inv = 1.f/sum;
    long obase = ((long)t*NB + b)*KP;
    #pragma unroll
    for (int s = 0; s < 8; ++s){
      int idx = s*64 + lane;
      if (idx < KP) attn_all[obase + idx] = __float2bfloat16(idx < NREL ? v[s]*inv : 0.f);
    }
  }
}

// ---------- dispatch 7: score GEMM (5056 blocks, MODE2) + gi GEMM (1536, MODE1) ----------
__global__ __launch_bounds__(256) void k_gemm_dual(
    const bf16* __restrict__ A2, const bf16* __restrict__ B2,
    void* __restrict__ C2, long ldc2, int K2, int nvalid2,
    double* __restrict__ sp, const int* __restrict__ trips, int nblk2,
    const bf16* __restrict__ A1, const bf16* __restrict__ B1,
    const float* __restrict__ bias1, void* __restrict__ C1, long ldc1, int K1)
{
  __shared__ __align__(16) bf16 sbuf[16384];   // 32KB -> 4 blocks/CU
  __shared__ float wsum[8];
  int bid = blockIdx.x;
  if (bid < nblk2){
    gemm128_body<2>(A2, 256, B2, 256, nullptr, C2, ldc2, K2, nvalid2, sp, trips,
                    sbuf, wsum, bid & 31, bid >> 5);
  } else {
    int idx = bid - nblk2;
    gemm128_body<1>(A1, KP, B1, KP, bias1, C1, ldc1, K1, 0, nullptr, nullptr,
                    sbuf, wsum, idx & 255, idx >> 8);
  }
}

// ---------- dispatch 8: fused 8-step GRU scan + match loss + final (ticket) ----------
__global__ __launch_bounds__(512) void k_scan(
    const bf16* __restrict__ gi_all,       // [8*NB][768], b_ih folded in
    const bf16* __restrict__ W_hh_bf,      // [768][256]
    const float* __restrict__ b_hh,
    const float* __restrict__ ph,          // [512][256] rows<460 valid
    const int* __restrict__ trips,
    double* __restrict__ dsum, int* __restrict__ done, float* __restrict__ outf)
{
  __shared__ __align__(16) bf16 hl[16*264];
  __shared__ __align__(16) bf16 gbuf[2][16*768];
  __shared__ float red[8];
  const int tid = threadIdx.x;
  const int lane = tid & 63, wave = tid >> 6;
  const int brow0 = blockIdx.x * 16;
  const int rA = lane & 15, kA = (lane >> 4) * 8;
  const int ci = lane & 15, rbase = (lane >> 4) * 4;
  float hreg[2][4] = {};
  float bh[3][2];
  #pragma unroll
  for (int f = 0; f < 2; ++f){
    int cf = wave*32 + f*16 + ci;
    bh[0][f] = b_hh[cf]; bh[1][f] = b_hh[256+cf]; bh[2][f] = b_hh[512+cf];
  }
  // preload W-frags for k-slices 0..5 (144 VGPR); slices 6,7 streamed from L2
  short8 warr[3][2][6];
  #pragma unroll
  for (int g = 0; g < 3; ++g)
    #pragma unroll
    for (int f = 0; f < 2; ++f)
      #pragma unroll
      for (int k = 0; k < 6; ++k)
        warr[g][f][k] = *(const short8*)(W_hh_bf + (g*256 + wave*32 + f*16 + rA)*256 + k*32 + kA);
  {
    const bf16* src = gi_all + (long)brow0 * 768;
    #pragma unroll
    for (int i = 0; i < 3; ++i){
      int off = (wave*3 + i)*512 + lane*8;
      gload16(src + off, gbuf[0] + off);
    }
  }
  int cur = 0;
  for (int t = 0; t < 8; ++t){
    f32x4 acc[3][2] = {};
    if (t > 0){
      #pragma unroll
      for (int k = 0; k < 8; ++k){
        short8 a = *(const short8*)(hl + rA*264 + k*32 + kA);
        #pragma unroll
        for (int g = 0; g < 3; ++g)
          #pragma unroll
          for (int f = 0; f < 2; ++f){
            short8 b;
            if (k < 6) b = warr[g][f][k];
            else b = *(const short8*)(W_hh_bf + (g*256 + wave*32 + f*16 + rA)*256 + k*32 + kA);
            acc[g][f] = __builtin_amdgcn_mfma_f32_16x16x32_bf16(a, b, acc[g][f], 0,0,0);
          }
      }
    }
    asm volatile("s_waitcnt lgkmcnt(0) vmcnt(0)" ::: "memory"); // hl reads retired; gi(t) staged
    __builtin_amdgcn_s_barrier();
    if (t < 7){
      const bf16* src = gi_all + ((long)(t+1)*NB + brow0) * 768;
      bf16* dst = gbuf[cur ^ 1];
      #pragma unroll
      for (int i = 0; i < 3; ++i){
        int off = (wave*3 + i)*512 + lane*8;
        gload16(src + off, dst + off);
      }
    }
    const bf16* gl = gbuf[cur];
    #pragma unroll
    for (int f = 0; f < 2; ++f){
      int cf = wave*32 + f*16 + ci;
      #pragma unroll
      for (int i = 0; i < 4; ++i){
        int rloc = rbase + i;
        float gir = __bfloat162float(gl[rloc*768 + cf]);
        float giz = __bfloat162float(gl[rloc*768 + 256 + cf]);
        float gin = __bfloat162float(gl[rloc*768 + 512 + cf]);
        float rg = sigmoidf_(gir + acc[0][f][i] + bh[0][f]);
        float zg = sigmoidf_(giz + acc[1][f][i] + bh[1][f]);
        float ng = tanhf(gin + rg*(acc[2][f][i] + bh[2][f]));
        float hn = (1.f - zg)*ng + zg*hreg[f][i];
        hreg[f][i] = hn;
        hl[rloc*264 + cf] = __float2bfloat16(hn);
      }
    }
    asm volatile("s_waitcnt lgkmcnt(0)" ::: "memory");  // hl writes + gbuf reads retired
    __builtin_amdgcn_s_barrier();
    cur ^= 1;
  }
  float d = 0.f;
  #pragma unroll
  for (int f = 0; f < 2; ++f){
    int cf = wave*32 + f*16 + ci;
    #pragma unroll
    for (int i = 0; i < 4; ++i){
      int rel = trips[(brow0 + rbase + i)*3 + 1];
      float diff = ph[rel*256 + cf] - hreg[f][i];
      d += diff*diff;
    }
  }
  #pragma unroll
  for (int off = 32; off >= 1; off >>= 1) d += __shfl_xor(d, off);
  if (lane == 0) red[wave] = d;
  __syncthreads();
  if (tid == 0){
    float s = 0.f;
    #pragma unroll
    for (int w = 0; w < 8; ++w) s += red[w];
    atomicAdd(dsum, (double)s);
    asm volatile("s_waitcnt vmcnt(0)" ::: "memory");     // dsum add at coherent point
    int ticket = atomicAdd(done, 1);
    if (ticket == (int)gridDim.x - 1){
      double m  = atomicAdd(dsum+0, 0.0);                // coherent RMW reads
      double sp = atomicAdd(dsum+1, 0.0);
      double pp = atomicAdd(dsum+2, 0.0);
      outf[0] = (float)(m / (4096.0*256.0));
      outf[1] = (float)((sp - pp) / (4096.0*20000.0));
    }
  }
}

extern "C" void kernel_launch(void* const* d_in, const int* in_sizes, int n_in,
                              void* d_out, int out_size, void* d_ws, size_t ws_size,
                              hipStream_t stream){
  const float* pre_emb = (const float*)d_in[0];
  const float* r_emb   = (const float*)d_in[1];
  const float* partial = (const float*)d_in[2];
  const float* W_map1  = (const float*)d_in[3];
  const float* b_map1  = (const float*)d_in[4];
  const float* W_map2  = (const float*)d_in[5];
  const float* b_map2  = (const float*)d_in[6];
  const float* W_h1    = (const float*)d_in[7];
  const float* b_h1    = (const float*)d_in[8];
  const float* W_h2    = (const float*)d_in[9];
  const float* b_h2    = (const float*)d_in[10];
  const float* W_attn  = (const float*)d_in[11];
  const float* b_attn  = (const float*)d_in[12];
  const float* W_align = (const float*)d_in[13];
  const float* b_align = (const float*)d_in[14];
  const float* W_ih    = (const float*)d_in[15];
  const float* W_hh    = (const float*)d_in[16];
  const float* b_ih    = (const float*)d_in[17];
  const float* b_hh    = (const float*)d_in[18];
  const int*   trips   = (const int*)d_in[19];
  float* out = (float*)d_out;

  // ---- workspace layout ----
  char* w = (char*)d_ws;
  auto alloc = [&](size_t bytes)->char*{
    char* r = w; w += (bytes + 255) & ~size_t(255); return r;
  };
  double* dsum      = (double*)alloc(128);   // [0]=match [1]=softplus [2]=pos, [4..]=ticket
  int*    done      = (int*)(dsum + 4);
  float* t1         = (float*)alloc(512*512*4);
  float* mapped     = (float*)alloc(512*256*4);
  float* a1         = (float*)alloc(512*256*4);
  float* th         = (float*)alloc(512*256*4);
  float* ph         = (float*)alloc(512*256*4);
  float* M_ih       = (float*)alloc(512*768*4);
  float* ghp        = (float*)alloc(512*768*4);
  float* attn_base  = (float*)alloc(512*512*4);
  bf16*  M_ihT      = (bf16*)alloc(768*KP*2);
  bf16*  W_hh_bf    = (bf16*)alloc(768*256*2);
  bf16*  W_align_bf = (bf16*)alloc(256*256*2);
  bf16*  Q_bf       = (bf16*)alloc((size_t)NENT_PAD*256*2);
  bf16*  P_bf       = (bf16*)alloc((size_t)NB*256*2);
  bf16*  attn_all   = (bf16*)alloc((size_t)8*NB*KP*2);
  bf16*  gi_all     = (bf16*)alloc((size_t)8*NB*768*2);
  bf16*  pre_bf     = attn_all;   // aliased: pre_bf dead before attn_all written

  // ---- dispatch 1: conversions + pad/dsum zero + G1 (t1 = r_emb@W_map1^T + b_map1) ----
  {
    int n0 = NENT*256/4, n1 = 768*256/4, n2 = 256*256/4;
    int n3 = (NENT_PAD-NENT)*256/4;
    int ntot = n0+n1+n2+n3+8;
    k_conv_g1<<<64 + (ntot+255)/256, 256, 0, stream>>>(
        (const float4*)pre_emb, (short4v*)pre_bf, n0,
        (const float4*)W_hh, (short4v*)W_hh_bf, n1,
        (const float4*)W_align, (short4v*)W_align_bf, n2,
        (short4v*)(pre_bf + (size_t)NENT*256), n3, dsum,
        r_emb, W_map1, b_map1, t1);
  }
  // ---- dispatch 2: G2 mapped = t1 @ W_map2^T + b_map2 ----
  k_fgemm<<<dim3(8,4),256,0,stream>>>(t1,512,512, W_map2,512, b_map2, mapped,256, 512, 0, nullptr, nullptr);
  // ---- dispatch 3: G3 {M_ih+M_ihT | a1 | th} + aligned GEMM (Q_bf) ----
  {
    FDesc d0 = { mapped, W_ih,   nullptr, M_ih, nullptr, M_ihT, 256, 256, 768, 256, 512, 1 };
    FDesc d1 = { mapped, W_attn, b_attn,  a1,   nullptr, nullptr, 256, 256, 256, 256, 512, 0 };
    FDesc d2 = { mapped, W_h1,   b_h1,    th,   nullptr, nullptr, 256, 256, 256, 256, 512, 0 };
    k_g3_aligned<<<160 + 316, 256, 0, stream>>>(d0, d1, d2, 12, 16,
                                                pre_bf, W_align_bf, b_align, Q_bf);
  }
  // ---- dispatch 4: G4 {ph} + G5 {attn_base} ----
  {
    FDesc d0 = { th, W_h2,   b_h2,    ph,        mapped,  nullptr, 256, 256, 256, 256, 512, 2 };
    FDesc d1 = { a1, mapped, nullptr, attn_base, nullptr, nullptr, 256, 256, 512, 256, 512, 0 };
    k_fgemm_multi<<<dim3(8,12),256,0,stream>>>(d0, d1, d1, 4, 12);
  }
  // ---- dispatch 5: G6 ghp = ph @ W_hh^T + b_hh ----
  k_fgemm<<<dim3(8,12),256,0,stream>>>(ph,256,512, W_hh,256, b_hh, ghp,768, 256, 0, nullptr, nullptr);
  // ---- dispatch 6: softmax + make_p (inline h2) ----
  k_soft_makep<<<NB/4 + NB,256,0,stream>>>(partial, attn_base, trips, attn_all,
                                           Q_bf, M_ih, ghp, ph, b_ih, P_bf);
  // ---- dispatch 7: score (MODE2) + gi (MODE1) merged ----
  k_gemm_dual<<<5056 + 1536, 256, 0, stream>>>(
      P_bf, Q_bf, out+2, NENT, 256, NENT, dsum+1, trips, 5056,
      attn_all, M_ihT, b_ih, gi_all, 768, KP);
  // ---- dispatch 8: scan + match loss + final ----
  k_scan<<<NB/16,512,0,stream>>>(gi_all, W_hh_bf, b_hh, ph, trips, dsum, done, out);
}

// Round 16
// 357.748 us; speedup vs baseline: 1.2281x; 1.0814x over previous
//
#include <hip/hip_runtime.h>
#include <hip/hip_bf16.h>

typedef __hip_bfloat16 bf16;
typedef __attribute__((ext_vector_type(8))) short short8;   // 8 bf16 (MFMA A/B frag)
typedef __attribute__((ext_vector_type(4))) float f32x4;    // MFMA C/D frag
typedef __attribute__((ext_vector_type(4))) short short4v;

#define NREL 460
#define KP   480      // padded K for attn GEMM (15*32)
#define NENT 20000
#define NENT_PAD 20224  // 158*128
#define NB   4096

__device__ inline float sigmoidf_(float x){ return 1.f/(1.f+__expf(-x)); }

// async global->LDS, 16B per lane. LDS dest = wave-uniform base + lane*16.
__device__ inline void gload16(const bf16* g, bf16* l){
  __builtin_amdgcn_global_load_lds(
      (const __attribute__((address_space(1))) unsigned int*)g,
      (__attribute__((address_space(3))) unsigned int*)l, 16, 0, 0);
}

// ---------- fp32 tiled GEMM body (LDS passed in: As/Bs each 32*68 floats) ----------
// 64x64 tile, 256 threads, 4x4 outputs/thread, K-tile 32 staged in LDS.
__device__ __forceinline__ void fgemm_body(
    const float* __restrict__ A, int lda, int arows,
    const float* __restrict__ B, int ldb,
    const float* __restrict__ bias,
    float* __restrict__ C, int ldc, int K, int mode,
    const float* __restrict__ add_src, bf16* __restrict__ ct_out,
    float* As, float* Bs, int bx, int by)
{
  const int tid = threadIdx.x;
  const int row0 = bx*64, col0 = by*64;
  const int tx = tid & 15, ty = tid >> 4;
  float acc[4][4] = {};
  for (int k0 = 0; k0 < K; k0 += 32){
    __syncthreads();
    #pragma unroll
    for (int s = 0; s < 2; ++s){
      int slot = tid + s*256;
      int r = slot >> 3, c4 = (slot & 7)*4;
      int ra = row0 + r; if (ra >= arows) ra = arows - 1;
      float4 v = *(const float4*)(A + (long)ra*lda + k0 + c4);
      As[(c4+0)*68+r] = v.x; As[(c4+1)*68+r] = v.y; As[(c4+2)*68+r] = v.z; As[(c4+3)*68+r] = v.w;
      float4 w = *(const float4*)(B + (long)(col0 + r)*ldb + k0 + c4);
      Bs[(c4+0)*68+r] = w.x; Bs[(c4+1)*68+r] = w.y; Bs[(c4+2)*68+r] = w.z; Bs[(c4+3)*68+r] = w.w;
    }
    __syncthreads();
    #pragma unroll
    for (int kk = 0; kk < 32; ++kk){
      float4 a4 = *(const float4*)(&As[kk*68 + ty*4]);
      float4 b4 = *(const float4*)(&Bs[kk*68 + tx*4]);
      float av[4] = {a4.x, a4.y, a4.z, a4.w};
      float bv[4] = {b4.x, b4.y, b4.z, b4.w};
      #pragma unroll
      for (int i = 0; i < 4; ++i)
        #pragma unroll
        for (int j = 0; j < 4; ++j) acc[i][j] += av[i]*bv[j];
    }
  }
  const int rb = row0 + ty*4, cb = col0 + tx*4;
  if (mode == 1){
    #pragma unroll
    for (int i = 0; i < 4; ++i){
      float4 v = {acc[i][0], acc[i][1], acc[i][2], acc[i][3]};
      *(float4*)(C + (long)(rb+i)*ldc + cb) = v;
      int rr = rb + i;
      if (rr < KP){
        #pragma unroll
        for (int j = 0; j < 4; ++j)
          ct_out[(cb+j)*KP + rr] = __float2bfloat16(rr < NREL ? acc[i][j] : 0.f);
      }
    }
  } else if (mode == 2){
    #pragma unroll
    for (int i = 0; i < 4; ++i){
      float4 v;
      #pragma unroll
      for (int j = 0; j < 4; ++j)
        ((float*)&v)[j] = 0.1f*(acc[i][j] + bias[cb+j]) + add_src[(long)(rb+i)*ldc + cb+j];
      *(float4*)(C + (long)(rb+i)*ldc + cb) = v;
    }
  } else {
    float bv[4] = {0,0,0,0};
    if (bias){ bv[0]=bias[cb]; bv[1]=bias[cb+1]; bv[2]=bias[cb+2]; bv[3]=bias[cb+3]; }
    #pragma unroll
    for (int i = 0; i < 4; ++i){
      float4 v = {acc[i][0]+bv[0], acc[i][1]+bv[1], acc[i][2]+bv[2], acc[i][3]+bv[3]};
      *(float4*)(C + (long)(rb+i)*ldc + cb) = v;
    }
  }
}

struct FDesc {
  const float* A; const float* B; const float* bias; float* C;
  const float* add; bf16* ct;
  int lda, ldb, ldc, K, arows, mode;
};

// ---------- 256-thread MFMA body (aligned GEMM only), 2-buffer, swizzled ----------
__device__ __forceinline__ void gemm128_body1(
    const bf16* __restrict__ A, int lda,
    const bf16* __restrict__ B, int ldb,
    const float* __restrict__ bias,
    bf16* __restrict__ C, long ldc, int K,
    bf16* sbuf, int bx, int by)
{
  const int tid = threadIdx.x;
  const int lane = tid & 63, wave = tid >> 6;
  const long row0 = (long)bx * 128;
  const long col0 = (long)by * 128;
  const int sr = tid >> 2;
  const int sc = ((tid & 3) ^ ((sr >> 1) & 3)) * 8;
  const bf16* Ag0 = A + (row0 + sr)*lda + sc;
  const bf16* Ag1 = A + (row0 + 64 + sr)*lda + sc;
  const bf16* Bg0 = B + (col0 + sr)*ldb + sc;
  const bf16* Bg1 = B + (col0 + 64 + sr)*ldb + sc;
  bf16* As_ = sbuf;          // [2][4096]
  bf16* Bs_ = sbuf + 8192;   // [2][4096]
  const int wr = (wave >> 1)*64, wc = (wave & 1)*64;
  const int rA = lane & 15;
  const int kA = ((lane >> 4) ^ ((rA >> 1) & 3)) * 8;
  f32x4 acc[4][4] = {};
  const int nt = K >> 5;
  gload16(Ag0, As_ + tid*8);
  gload16(Ag1, As_ + 2048 + tid*8);
  gload16(Bg0, Bs_ + tid*8);
  gload16(Bg1, Bs_ + 2048 + tid*8);
  int cur = 0;
  for (int t = 0; t < nt; ++t){
    if (t + 1 < nt){
      const int k0 = (t+1) << 5;
      const int nxt = cur ^ 1;
      gload16(Ag0 + k0, As_ + nxt*4096 + tid*8);
      gload16(Ag1 + k0, As_ + nxt*4096 + 2048 + tid*8);
      gload16(Bg0 + k0, Bs_ + nxt*4096 + tid*8);
      gload16(Bg1 + k0, Bs_ + nxt*4096 + 2048 + tid*8);
      asm volatile("s_waitcnt vmcnt(4)" ::: "memory");
    } else {
      asm volatile("s_waitcnt vmcnt(0)" ::: "memory");
    }
    __builtin_amdgcn_s_barrier();
    short8 a[4], b[4];
    #pragma unroll
    for (int m = 0; m < 4; ++m) a[m] = *(const short8*)(As_ + cur*4096 + (wr + m*16 + rA)*32 + kA);
    #pragma unroll
    for (int n = 0; n < 4; ++n) b[n] = *(const short8*)(Bs_ + cur*4096 + (wc + n*16 + rA)*32 + kA);
    asm volatile("s_waitcnt lgkmcnt(0)" ::: "memory");
    __builtin_amdgcn_s_barrier();
    #pragma unroll
    for (int m = 0; m < 4; ++m)
      #pragma unroll
      for (int n = 0; n < 4; ++n)
        acc[m][n] = __builtin_amdgcn_mfma_f32_16x16x32_bf16(a[m], b[n], acc[m][n], 0,0,0);
    cur ^= 1;
  }
  const int ri = (lane >> 4)*4, ci = lane & 15;
  __syncthreads();
  bf16* epi = sbuf + wave*1152;         // 16 rows x 72 bf16
  const int rrow = lane >> 2, q = lane & 3;
  #pragma unroll
  for (int m = 0; m < 4; ++m){
    #pragma unroll
    for (int n = 0; n < 4; ++n){
      long c = col0 + wc + n*16 + ci;
      float bv = bias ? bias[c] : 0.f;
      #pragma unroll
      for (int i = 0; i < 4; ++i)
        epi[(ri+i)*72 + n*16 + ci] = __float2bfloat16(acc[m][n][i] + bv);
    }
    long gr = row0 + wr + m*16 + rrow;
    bf16* gp = C + gr*ldc + col0 + wc + q*16;
    const bf16* lp = epi + rrow*72 + q*16;
    *(short8*)(gp)     = *(const short8*)(lp);
    *(short8*)(gp + 8) = *(const short8*)(lp + 8);
  }
}

// ---------- 512-thread MFMA body: 128x128 tile, 8 waves of 64x32 ----------
// acc[4][2] = 32 AGPR/thread (vs 64): raises reg-limited occupancy 3->4 waves/SIMD.
// 2-buffer LDS (32KB), granule-swizzled; 1 gload16/thread per operand.
// MODE 1: bf16 out (+bias). MODE 2: score epilogue.
template<int MODE>
__device__ __forceinline__ void gemm512_body(
    const bf16* __restrict__ A, int lda,
    const bf16* __restrict__ B, int ldb,
    const float* __restrict__ bias,
    void* __restrict__ C, long ldc,
    int K, int n_valid, double* __restrict__ sp_sum,
    const int* __restrict__ trips,
    bf16* sbuf, float* wsum, int bx, int by)
{
  const int tid = threadIdx.x;
  const int lane = tid & 63, wave = tid >> 6;   // 8 waves
  const long row0 = (long)bx * 128;
  const long col0 = (long)by * 128;
  const int sr = tid >> 2;                      // 0..127
  const int sc = ((tid & 3) ^ ((sr >> 1) & 3)) * 8;
  const bf16* Ag = A + (row0 + sr)*lda + sc;
  const bf16* Bg = B + (col0 + sr)*ldb + sc;
  bf16* As_ = sbuf;          // [2][4096]
  bf16* Bs_ = sbuf + 8192;   // [2][4096]
  const int wr = (wave >> 2)*64, wc = (wave & 3)*32;
  const int rA = lane & 15;
  const int kA = ((lane >> 4) ^ ((rA >> 1) & 3)) * 8;
  f32x4 acc[4][2] = {};
  const int nt = K >> 5;
  gload16(Ag, As_ + tid*8);
  gload16(Bg, Bs_ + tid*8);
  int cur = 0;
  for (int t = 0; t < nt; ++t){
    if (t + 1 < nt){
      const int k0 = (t+1) << 5;
      const int nxt = cur ^ 1;
      gload16(Ag + k0, As_ + nxt*4096 + tid*8);
      gload16(Bg + k0, Bs_ + nxt*4096 + tid*8);
      asm volatile("s_waitcnt vmcnt(2)" ::: "memory");   // tile t arrived
    } else {
      asm volatile("s_waitcnt vmcnt(0)" ::: "memory");
    }
    __builtin_amdgcn_s_barrier();                        // tile t visible
    short8 a[4], b[2];
    #pragma unroll
    for (int m = 0; m < 4; ++m) a[m] = *(const short8*)(As_ + cur*4096 + (wr + m*16 + rA)*32 + kA);
    #pragma unroll
    for (int n = 0; n < 2; ++n) b[n] = *(const short8*)(Bs_ + cur*4096 + (wc + n*16 + rA)*32 + kA);
    asm volatile("s_waitcnt lgkmcnt(0)" ::: "memory");   // frags in regs
    __builtin_amdgcn_s_barrier();                        // buf free for restage
    #pragma unroll
    for (int m = 0; m < 4; ++m)
      #pragma unroll
      for (int n = 0; n < 2; ++n)
        acc[m][n] = __builtin_amdgcn_mfma_f32_16x16x32_bf16(a[m], b[n], acc[m][n], 0,0,0);
    cur ^= 1;
  }
  const int ri = (lane >> 4)*4, ci = lane & 15;
  __syncthreads();   // staging LDS -> epilogue bounce
  if constexpr (MODE == 1){
    bf16* epi = sbuf + wave*640;          // 16 rows x 40 bf16 (per-wave)
    const int rw = lane >> 2, q = lane & 3;
    #pragma unroll
    for (int m = 0; m < 4; ++m){
      #pragma unroll
      for (int n = 0; n < 2; ++n){
        long c = col0 + wc + n*16 + ci;
        float bv = bias ? bias[c] : 0.f;
        #pragma unroll
        for (int i = 0; i < 4; ++i)
          epi[(ri+i)*40 + n*16 + ci] = __float2bfloat16(acc[m][n][i] + bv);
      }
      long gr = row0 + wr + m*16 + rw;
      bf16* gp = (bf16*)C + gr*ldc + col0 + wc + q*8;
      *(short8*)(gp) = *(const short8*)(epi + rw*40 + q*8);
    }
  } else {
    float* epi = (float*)sbuf + wave*576;   // 16 rows x 36 f32, cols shifted +2
    const int rw = lane >> 2, q = lane & 3;
    const bool maybe = (col0 + wc) < 464;
    float spart = 0.f, ppart = 0.f;
    #pragma unroll
    for (int m = 0; m < 4; ++m){
      int obj[4];
      if (maybe){
        #pragma unroll
        for (int i = 0; i < 4; ++i)
          obj[i] = trips[3*(int)(row0 + wr + m*16 + ri + i) + 2];
      }
      #pragma unroll
      for (int n = 0; n < 2; ++n){
        long c = col0 + wc + n*16 + ci;
        bool cv = (c < n_valid);
        #pragma unroll
        for (int i = 0; i < 4; ++i){
          float v = acc[m][n][i];
          float sg = 0.f;
          if (cv){
            float e = __expf(-fabsf(v));
            float tt = 1.f + e;
            float rr = __builtin_amdgcn_rcpf(tt);
            sg = (v >= 0.f) ? rr : 1.f - rr;
            spart += fmaxf(v, 0.f) + e*(0.9404f - 0.2537f*e);
            if (maybe && c == obj[i]) ppart += v;
          }
          epi[(ri+i)*36 + n*16 + ci + 2] = sg;
        }
      }
      long gr = row0 + wr + m*16 + rw;
      long c8 = col0 + wc + q*8;
      if (c8 < n_valid){                       // 8 | 20000 -> whole chunk valid
        float* gp = (float*)C + gr*ldc + c8;   // base ≡ 8 (mod 16)
        const float* lp = epi + rw*36 + q*8 + 2;
        *(float2*)(gp)     = *(const float2*)(lp);
        *(float4*)(gp + 2) = *(const float4*)(lp + 2);
        *(float2*)(gp + 6) = *(const float2*)(lp + 6);
      }
    }
    #pragma unroll
    for (int off = 32; off >= 1; off >>= 1){
      spart += __shfl_xor(spart, off);
      ppart += __shfl_xor(ppart, off);
    }
    if (lane == 0){ wsum[wave] = spart; wsum[8+wave] = ppart; }
    __syncthreads();
    if (tid == 0){
      float s = 0.f;
      #pragma unroll
      for (int w = 0; w < 8; ++w) s += wsum[w];
      atomicAdd(sp_sum, (double)s);
    }
    if (tid == 1){
      float p = 0.f;
      #pragma unroll
      for (int w = 0; w < 8; ++w) p += wsum[8+w];
      atomicAdd(sp_sum+1, (double)p);
    }
  }
}

// ---------- dispatch 1: conversions + pad/acc zero + G1 GEMM ----------
__global__ __launch_bounds__(256) void k_conv_g1(
    const float4* __restrict__ s0, short4v* __restrict__ d0, int n0,
    const float4* __restrict__ s1, short4v* __restrict__ d1, int n1,
    const float4* __restrict__ s2, short4v* __restrict__ d2, int n2,
    short4v* __restrict__ pad0, int n3, double* __restrict__ dz,
    const float* __restrict__ gA, const float* __restrict__ gB,
    const float* __restrict__ gbias, float* __restrict__ gC)
{
  __shared__ __align__(16) float As[32*68];
  __shared__ __align__(16) float Bs[32*68];
  int bid = blockIdx.x;
  if (bid < 64){
    fgemm_body(gA,256,NREL, gB,256, gbias, gC,512, 256, 0, nullptr,nullptr,
               As, Bs, bid&7, bid>>3);
    return;
  }
  int i = (bid-64)*256 + threadIdx.x;
  if (i < n0+n1+n2){
    const float4* s; short4v* d; int j;
    if (i < n0){ s = s0; d = d0; j = i; }
    else if (i < n0+n1){ s = s1; d = d1; j = i-n0; }
    else { s = s2; d = d2; j = i-n0-n1; }
    float4 v = s[j];
    bf16 a = __float2bfloat16(v.x), b = __float2bfloat16(v.y);
    bf16 c = __float2bfloat16(v.z), e = __float2bfloat16(v.w);
    short4v o; o.x = *(short*)&a; o.y = *(short*)&b; o.z = *(short*)&c; o.w = *(short*)&e;
    d[j] = o;
  } else if (i < n0+n1+n2+n3){
    short4v z = {0,0,0,0};
    pad0[i - (n0+n1+n2)] = z;
  } else if (i < n0+n1+n2+n3+8){
    dz[i - (n0+n1+n2+n3)] = 0.0;   // dsum[0..2] + ticket counters
  }
}

__global__ __launch_bounds__(256) void k_fgemm(
    const float* A, int lda, int arows, const float* B, int ldb,
    const float* bias, float* C, int ldc, int K, int mode,
    const float* add_src, bf16* ct_out){
  __shared__ __align__(16) float As[32*68];
  __shared__ __align__(16) float Bs[32*68];
  fgemm_body(A, lda, arows, B, ldb, bias, C, ldc, K, mode, add_src, ct_out,
             As, Bs, blockIdx.x, blockIdx.y);
}

__global__ __launch_bounds__(256) void k_fgemm_multi(FDesc d0, FDesc d1, FDesc d2,
                                                     int y1, int y2){
  __shared__ __align__(16) float As[32*68];
  __shared__ __align__(16) float Bs[32*68];
  int y = blockIdx.y;
  FDesc d; int by;
  if (y < y1){ d = d0; by = y; }
  else if (y < y2){ d = d1; by = y - y1; }
  else { d = d2; by = y - y2; }
  fgemm_body(d.A, d.lda, d.arows, d.B, d.ldb, d.bias, d.C, d.ldc, d.K, d.mode,
             d.add, d.ct, As, Bs, blockIdx.x, by);
}

// ---------- dispatch 3: G3 multi (160 blocks) + aligned MFMA GEMM (316 blocks) ----------
__global__ __launch_bounds__(256) void k_g3_aligned(
    FDesc d0, FDesc d1, FDesc d2, int y1, int y2,
    const bf16* __restrict__ pA, const bf16* __restrict__ pB,
    const float* __restrict__ pbias, bf16* __restrict__ pC)
{
  __shared__ __align__(16) char smem[34816];
  int bid = blockIdx.x;
  if (bid < 160){
    int bx = bid & 7, y = bid >> 3;
    FDesc d; int by;
    if (y < y1){ d = d0; by = y; }
    else if (y < y2){ d = d1; by = y - y1; }
    else { d = d2; by = y - y2; }
    fgemm_body(d.A, d.lda, d.arows, d.B, d.ldb, d.bias, d.C, d.ldc, d.K, d.mode,
               d.add, d.ct, (float*)smem, (float*)(smem + 17408), bx, by);
  } else {
    int idx = bid - 160;
    gemm128_body1(pA, 256, pB, 256, pbias, pC, 256, 256,
                  (bf16*)smem, idx % 158, idx / 158);
  }
}

// ---------- dispatch 6: softmax (blocks [0,NB/4)) + make_p with inline h2 ----------
__global__ __launch_bounds__(256) void k_soft_makep(const float* __restrict__ partial,
    const float* __restrict__ attn_base, const int* __restrict__ trips,
    bf16* __restrict__ attn_all,
    const bf16* __restrict__ Qbf,
    const float* __restrict__ M_ih, const float* __restrict__ ghp,
    const float* __restrict__ ph, const float* __restrict__ b_ih,
    bf16* __restrict__ P){
  int bid = blockIdx.x;
  if (bid >= NB/4){
    int i = (bid - NB/4)*256 + threadIdx.x;   // 4096*256
    int b = i >> 8, k = i & 255;
    int s = trips[b*3+0], rel = trips[b*3+1];
    long rb = (long)rel*768;
    float rg = sigmoidf_(M_ih[rb+k]     + b_ih[k]     + ghp[rb+k]);
    float zg = sigmoidf_(M_ih[rb+256+k] + b_ih[256+k] + ghp[rb+256+k]);
    float ng = tanhf    (M_ih[rb+512+k] + b_ih[512+k] + rg*ghp[rb+512+k]);
    float h2v = (1.f - zg)*ng + zg*ph[rel*256+k];
    P[i] = __float2bfloat16(__bfloat162float(Qbf[(long)s*256+k]) * h2v);
    return;
  }
  int wave = threadIdx.x >> 6, lane = threadIdx.x & 63;
  int b = bid*4 + wave;
  int rel = trips[b*3+1];
  const float* base = attn_base + (long)rel*512;
  float bs[8];
  #pragma unroll
  for (int s = 0; s < 8; ++s){
    int idx = s*64 + lane;
    bs[s] = (idx < NREL) ? base[idx] : 0.f;
  }
  const float* cur0 = partial + (long)b*4600 + 2*NREL;
  for (int t = 0; t < 8; ++t){
    const float* cur = cur0 + t*NREL;
    float v[8]; float mx = -1e30f;
    #pragma unroll
    for (int s = 0; s < 8; ++s){
      int idx = s*64 + lane;
      float val = -1e30f;
      if (idx < NREL){
        float pz = cur[idx]*bs[s];
        val = (pz == 0.f) ? -1e9f : pz;
      }
      v[s] = val; mx = fmaxf(mx, val);
    }
    #pragma unroll
    for (int off = 32; off >= 1; off >>= 1) mx = fmaxf(mx, __shfl_xor(mx, off));
    float sum = 0.f;
    #pragma unroll
    for (int s = 0; s < 8; ++s){
      int idx = s*64 + lane;
      if (idx < NREL){ v[s] = __expf(v[s]-mx); sum += v[s]; }
    }
    #pragma unroll
    for (int off = 32; off >= 1; off >>= 1) sum += __shfl_xor(sum, off);
    float inv = 1.f/sum;
    long obase = ((long)t*NB + b)*KP;
    #pragma unroll
    for (int s = 0; s < 8; ++s){
      int idx = s*64 + lane;
      if (idx < KP) attn_all[obase + idx] = __float2bfloat16(idx < NREL ? v[s]*inv : 0.f);
    }
  }
}

// ---------- dispatch 7 (512 threads): score (5056, MODE2) + gi (1536, MODE1) ----------
__global__ __launch_bounds__(512, 4) void k_gemm_dual(
    const bf16* __restrict__ A2, const bf16* __restrict__ B2,
    void* __restrict__ C2, long ldc2, int K2, int nvalid2,
    double* __restrict__ sp, const int* __restrict__ trips, int nblk2,
    const bf16* __restrict__ A1, const bf16* __restrict__ B1,
    const float* __restrict__ bias1, void* __restrict__ C1, long ldc1, int K1)
{
  __shared__ __align__(16) bf16 sbuf[16384];   // 32KB
  __shared__ float wsum[16];
  int bid = blockIdx.x;
  if (bid < nblk2){
    gemm512_body<2>(A2, 256, B2, 256, nullptr, C2, ldc2, K2, nvalid2, sp, trips,
                    sbuf, wsum, bid & 31, bid >> 5);
  } else {
    int idx = bid - nblk2;
    gemm512_body<1>(A1, KP, B1, KP, bias1, C1, ldc1, K1, 0, nullptr, nullptr,
                    sbuf, wsum, idx & 255, idx >> 8);
  }
}

// ---------- dispatch 8: fused 8-step GRU scan + match loss + final (ticket) ----------
__global__ __launch_bounds__(512) void k_scan(
    const bf16* __restrict__ gi_all,       // [8*NB][768], b_ih folded in
    const bf16* __restrict__ W_hh_bf,      // [768][256]
    const float* __restrict__ b_hh,
    const float* __restrict__ ph,          // [512][256] rows<460 valid
    const int* __restrict__ trips,
    double* __restrict__ dsum, int* __restrict__ done, float* __restrict__ outf)
{
  __shared__ __align__(16) bf16 hl[16*264];
  __shared__ __align__(16) bf16 gbuf[2][16*768];
  __shared__ float red[8];
  const int tid = threadIdx.x;
  const int lane = tid & 63, wave = tid >> 6;
  const int brow0 = blockIdx.x * 16;
  const int rA = lane & 15, kA = (lane >> 4) * 8;
  const int ci = lane & 15, rbase = (lane >> 4) * 4;
  float hreg[2][4] = {};
  float bh[3][2];
  #pragma unroll
  for (int f = 0; f < 2; ++f){
    int cf = wave*32 + f*16 + ci;
    bh[0][f] = b_hh[cf]; bh[1][f] = b_hh[256+cf]; bh[2][f] = b_hh[512+cf];
  }
  short8 warr[3][2][6];
  #pragma unroll
  for (int g = 0; g < 3; ++g)
    #pragma unroll
    for (int f = 0; f < 2; ++f)
      #pragma unroll
      for (int k = 0; k < 6; ++k)
        warr[g][f][k] = *(const short8*)(W_hh_bf + (g*256 + wave*32 + f*16 + rA)*256 + k*32 + kA);
  {
    const bf16* src = gi_all + (long)brow0 * 768;
    #pragma unroll
    for (int i = 0; i < 3; ++i){
      int off = (wave*3 + i)*512 + lane*8;
      gload16(src + off, gbuf[0] + off);
    }
  }
  int cur = 0;
  for (int t = 0; t < 8; ++t){
    f32x4 acc[3][2] = {};
    if (t > 0){
      #pragma unroll
      for (int k = 0; k < 8; ++k){
        short8 a = *(const short8*)(hl + rA*264 + k*32 + kA);
        #pragma unroll
        for (int g = 0; g < 3; ++g)
          #pragma unroll
          for (int f = 0; f < 2; ++f){
            short8 b;
            if (k < 6) b = warr[g][f][k];
            else b = *(const short8*)(W_hh_bf + (g*256 + wave*32 + f*16 + rA)*256 + k*32 + kA);
            acc[g][f] = __builtin_amdgcn_mfma_f32_16x16x32_bf16(a, b, acc[g][f], 0,0,0);
          }
      }
    }
    asm volatile("s_waitcnt lgkmcnt(0) vmcnt(0)" ::: "memory");
    __builtin_amdgcn_s_barrier();
    if (t < 7){
      const bf16* src = gi_all + ((long)(t+1)*NB + brow0) * 768;
      bf16* dst = gbuf[cur ^ 1];
      #pragma unroll
      for (int i = 0; i < 3; ++i){
        int off = (wave*3 + i)*512 + lane*8;
        gload16(src + off, dst + off);
      }
    }
    const bf16* gl = gbuf[cur];
    #pragma unroll
    for (int f = 0; f < 2; ++f){
      int cf = wave*32 + f*16 + ci;
      #pragma unroll
      for (int i = 0; i < 4; ++i){
        int rloc = rbase + i;
        float gir = __bfloat162float(gl[rloc*768 + cf]);
        float giz = __bfloat162float(gl[rloc*768 + 256 + cf]);
        float gin = __bfloat162float(gl[rloc*768 + 512 + cf]);
        float rg = sigmoidf_(gir + acc[0][f][i] + bh[0][f]);
        float zg = sigmoidf_(giz + acc[1][f][i] + bh[1][f]);
        float ng = tanhf(gin + rg*(acc[2][f][i] + bh[2][f]));
        float hn = (1.f - zg)*ng + zg*hreg[f][i];
        hreg[f][i] = hn;
        hl[rloc*264 + cf] = __float2bfloat16(hn);
      }
    }
    asm volatile("s_waitcnt lgkmcnt(0)" ::: "memory");
    __builtin_amdgcn_s_barrier();
    cur ^= 1;
  }
  float d = 0.f;
  #pragma unroll
  for (int f = 0; f < 2; ++f){
    int cf = wave*32 + f*16 + ci;
    #pragma unroll
    for (int i = 0; i < 4; ++i){
      int rel = trips[(brow0 + rbase + i)*3 + 1];
      float diff = ph[rel*256 + cf] - hreg[f][i];
      d += diff*diff;
    }
  }
  #pragma unroll
  for (int off = 32; off >= 1; off >>= 1) d += __shfl_xor(d, off);
  if (lane == 0) red[wave] = d;
  __syncthreads();
  if (tid == 0){
    float s = 0.f;
    #pragma unroll
    for (int w = 0; w < 8; ++w) s += red[w];
    atomicAdd(dsum, (double)s);
    asm volatile("s_waitcnt vmcnt(0)" ::: "memory");
    int ticket = atomicAdd(done, 1);
    if (ticket == (int)gridDim.x - 1){
      double m  = atomicAdd(dsum+0, 0.0);
      double sp = atomicAdd(dsum+1, 0.0);
      double pp = atomicAdd(dsum+2, 0.0);
      outf[0] = (float)(m / (4096.0*256.0));
      outf[1] = (float)((sp - pp) / (4096.0*20000.0));
    }
  }
}

extern "C" void kernel_launch(void* const* d_in, const int* in_sizes, int n_in,
                              void* d_out, int out_size, void* d_ws, size_t ws_size,
                              hipStream_t stream){
  const float* pre_emb = (const float*)d_in[0];
  const float* r_emb   = (const float*)d_in[1];
  const float* partial = (const float*)d_in[2];
  const float* W_map1  = (const float*)d_in[3];
  const float* b_map1  = (const float*)d_in[4];
  const float* W_map2  = (const float*)d_in[5];
  const float* b_map2  = (const float*)d_in[6];
  const float* W_h1    = (const float*)d_in[7];
  const float* b_h1    = (const float*)d_in[8];
  const float* W_h2    = (const float*)d_in[9];
  const float* b_h2    = (const float*)d_in[10];
  const float* W_attn  = (const float*)d_in[11];
  const float* b_attn  = (const float*)d_in[12];
  const float* W_align = (const float*)d_in[13];
  const float* b_align = (const float*)d_in[14];
  const float* W_ih    = (const float*)d_in[15];
  const float* W_hh    = (const float*)d_in[16];
  const float* b_ih    = (const float*)d_in[17];
  const float* b_hh    = (const float*)d_in[18];
  const int*   trips   = (const int*)d_in[19];
  float* out = (float*)d_out;

  // ---- workspace layout ----
  char* w = (char*)d_ws;
  auto alloc = [&](size_t bytes)->char*{
    char* r = w; w += (bytes + 255) & ~size_t(255); return r;
  };
  double* dsum      = (double*)alloc(128);   // [0]=match [1]=softplus [2]=pos, [4..]=ticket
  int*    done      = (int*)(dsum + 4);
  float* t1         = (float*)alloc(512*512*4);
  float* mapped     = (float*)alloc(512*256*4);
  float* a1         = (float*)alloc(512*256*4);
  float* th         = (float*)alloc(512*256*4);
  float* ph         = (float*)alloc(512*256*4);
  float* M_ih       = (float*)alloc(512*768*4);
  float* ghp        = (float*)alloc(512*768*4);
  float* attn_base  = (float*)alloc(512*512*4);
  bf16*  M_ihT      = (bf16*)alloc(768*KP*2);
  bf16*  W_hh_bf    = (bf16*)alloc(768*256*2);
  bf16*  W_align_bf = (bf16*)alloc(256*256*2);
  bf16*  Q_bf       = (bf16*)alloc((size_t)NENT_PAD*256*2);
  bf16*  P_bf       = (bf16*)alloc((size_t)NB*256*2);
  bf16*  attn_all   = (bf16*)alloc((size_t)8*NB*KP*2);
  bf16*  gi_all     = (bf16*)alloc((size_t)8*NB*768*2);
  bf16*  pre_bf     = attn_all;   // aliased: pre_bf dead before attn_all written

  // ---- dispatch 1: conversions + pad/dsum zero + G1 ----
  {
    int n0 = NENT*256/4, n1 = 768*256/4, n2 = 256*256/4;
    int n3 = (NENT_PAD-NENT)*256/4;
    int ntot = n0+n1+n2+n3+8;
    k_conv_g1<<<64 + (ntot+255)/256, 256, 0, stream>>>(
        (const float4*)pre_emb, (short4v*)pre_bf, n0,
        (const float4*)W_hh, (short4v*)W_hh_bf, n1,
        (const float4*)W_align, (short4v*)W_align_bf, n2,
        (short4v*)(pre_bf + (size_t)NENT*256), n3, dsum,
        r_emb, W_map1, b_map1, t1);
  }
  // ---- dispatch 2: G2 ----
  k_fgemm<<<dim3(8,4),256,0,stream>>>(t1,512,512, W_map2,512, b_map2, mapped,256, 512, 0, nullptr, nullptr);
  // ---- dispatch 3: G3 + aligned GEMM ----
  {
    FDesc d0 = { mapped, W_ih,   nullptr, M_ih, nullptr, M_ihT, 256, 256, 768, 256, 512, 1 };
    FDesc d1 = { mapped, W_attn, b_attn,  a1,   nullptr, nullptr, 256, 256, 256, 256, 512, 0 };
    FDesc d2 = { mapped, W_h1,   b_h1,    th,   nullptr, nullptr, 256, 256, 256, 256, 512, 0 };
    k_g3_aligned<<<160 + 316, 256, 0, stream>>>(d0, d1, d2, 12, 16,
                                                pre_bf, W_align_bf, b_align, Q_bf);
  }
  // ---- dispatch 4: G4 + G5 ----
  {
    FDesc d0 = { th, W_h2,   b_h2,    ph,        mapped,  nullptr, 256, 256, 256, 256, 512, 2 };
    FDesc d1 = { a1, mapped, nullptr, attn_base, nullptr, nullptr, 256, 256, 512, 256, 512, 0 };
    k_fgemm_multi<<<dim3(8,12),256,0,stream>>>(d0, d1, d1, 4, 12);
  }
  // ---- dispatch 5: G6 ----
  k_fgemm<<<dim3(8,12),256,0,stream>>>(ph,256,512, W_hh,256, b_hh, ghp,768, 256, 0, nullptr, nullptr);
  // ---- dispatch 6: softmax + make_p ----
  k_soft_makep<<<NB/4 + NB,256,0,stream>>>(partial, attn_base, trips, attn_all,
                                           Q_bf, M_ih, ghp, ph, b_ih, P_bf);
  // ---- dispatch 7: score + gi merged (512 threads) ----
  k_gemm_dual<<<5056 + 1536, 512, 0, stream>>>(
      P_bf, Q_bf, out+2, NENT, 256, NENT, dsum+1, trips, 5056,
      attn_all, M_ihT, b_ih, gi_all, 768, KP);
  // ---- dispatch 8: scan + match loss + final ----
  k_scan<<<NB/16,512,0,stream>>>(gi_all, W_hh_bf, b_hh, ph, trips, dsum, done, out);
}